// Round 10
// baseline (465.426 us; speedup 1.0000x reference)
//
#include <hip/hip_runtime.h>
#include <hip/hip_bf16.h>

using bf16 = __hip_bfloat16;
typedef __attribute__((ext_vector_type(4))) float f32x4;
typedef __attribute__((ext_vector_type(8))) short bf16x8;

__device__ __forceinline__ unsigned short bfbits(float f) {
    bf16 h = __float2bfloat16(f);
    return __builtin_bit_cast(unsigned short, h);
}

__device__ __forceinline__ void g2l16(const void* g, void* l) {
    __builtin_amdgcn_global_load_lds(
        (const __attribute__((address_space(1))) unsigned int*)g,
        (__attribute__((address_space(3))) unsigned int*)l, 16, 0, 0);
}

// ---------------- fused cast f32 -> bf16 for all 8 tensors (1 launch) ----------------
struct CastArgs {
    const float* src[8];
    int end[8];   // prefix ends in float4 units; end[7] = 6815744
};
__global__ __launch_bounds__(256)
void castall(CastArgs a, ushort4* __restrict__ out) {
    int stride = gridDim.x * blockDim.x;
    for (int i = blockIdx.x * blockDim.x + threadIdx.x; i < 6815744; i += stride) {
        const float* sp; int beg;
        if      (i < a.end[0]) { sp = a.src[0]; beg = 0; }
        else if (i < a.end[1]) { sp = a.src[1]; beg = a.end[0]; }
        else if (i < a.end[2]) { sp = a.src[2]; beg = a.end[1]; }
        else if (i < a.end[3]) { sp = a.src[3]; beg = a.end[2]; }
        else if (i < a.end[4]) { sp = a.src[4]; beg = a.end[3]; }
        else if (i < a.end[5]) { sp = a.src[5]; beg = a.end[4]; }
        else if (i < a.end[6]) { sp = a.src[6]; beg = a.end[5]; }
        else                   { sp = a.src[7]; beg = a.end[6]; }
        float4 v = reinterpret_cast<const float4*>(sp)[i - beg];
        ushort4 o;
        o.x = bfbits(v.x); o.y = bfbits(v.y); o.z = bfbits(v.z); o.w = bfbits(v.w);
        out[i] = o;
    }
}

// ======= 256x128-tile 8-wave GEMM: R4 ring-3 schedule, sized for 2 blocks/CU =======
// C = A @ B^T. A:[M,ldk] bf16 rm; Bm:[N,ldk] bf16 rm. BK=32.
// LDS ring-3 x 24KB (A 16KB = 2 halves + B 8KB), staged 2 K-tiles ahead,
// 1 barrier + 1 counted vmcnt(3) per K-tile. Regs ~110 <= 128 -> 4 waves/SIMD
// (2 co-resident blocks; TLP fills barrier/drain windows, m114 mechanism).
// Wave (wr,wc): wr in {0,1} x 128 rows, wc in {0..3} x 32 cols -> acc[8][2].
// EPI 0: QKV scatter (+per-tensor bias); Q,K -> [B,H,S,DK], V -> [B,H,DK,S] transposed
// EPI 1: relu(acc+bias) -> bf16 [M,N]
// EPI 2: raw f32 acc -> outp + slice*M*N  (split-K partials)
template<int EPI, int SPLITK>
__global__ __launch_bounds__(512, 4)
void gemm256(const bf16* __restrict__ A, const bf16* __restrict__ Bm,
             int N, int ldk, int kloop,
             const float* __restrict__ bias0, const float* __restrict__ bias1,
             const float* __restrict__ bias2,
             void* __restrict__ outp,
             bf16* __restrict__ q_o, bf16* __restrict__ k_o, bf16* __restrict__ v_o) {
    __shared__ __align__(16) char lds[73728];
    const int tid = threadIdx.x;
    const int lane = tid & 63, wave = tid >> 6;
    const int rlo = lane & 15, g = lane >> 4;
    const int wr = wave >> 2, wc = wave & 3;
    const int nbn = N >> 7;
    const int nwg = gridDim.x;
    int wg = (int)blockIdx.x;
    wg = (wg & 7) * (nwg >> 3) + (wg >> 3);   // XCD swizzle (nwg % 8 == 0)
    int slice = 0;
    if constexpr (SPLITK) {
        int half = nwg >> 1;
        slice = (wg >= half) ? 1 : 0;
        wg -= slice * half;
    }
    const int bm = wg / nbn, bn = wg % nbn;
    const size_t ldb = (size_t)ldk * 2;
    const char* abase = (const char*)A + ((size_t)bm << 8) * ldb + (size_t)slice * kloop * 2;
    const char* bbase = (const char*)Bm + ((size_t)bn << 7) * ldb + (size_t)slice * kloop * 2;

    // staging: thread t owns LDS bytes [t*16, t*16+16) of each 8 KB region.
    const int P = tid * 16;
    const int R = P >> 7;
    const int qs = (P & 127) ^ ((R & 7) << 4);          // unswizzle
    const size_t goff0 = (size_t)(R * 2 + (qs >> 6)) * ldb + (qs & 63);
    const size_t ghalf = (size_t)128 * ldb;

    // ds_read lane-constant inner offset (paired-row + 3-bit XOR swizzle)
    const int o_in = (((rlo & 1) << 6) | (g << 4)) ^ (((rlo >> 1) & 7) << 4);
    const int aoff = wr * 8192 + (rlo >> 1) * 128 + o_in;
    const int boff = 16384 + wc * 2048 + (rlo >> 1) * 128 + o_in;

    const f32x4 fz = {0.f, 0.f, 0.f, 0.f};
    f32x4 acc[8][2];
#pragma unroll
    for (int i = 0; i < 8; ++i)
#pragma unroll
        for (int j = 0; j < 2; ++j) acc[i][j] = fz;

    auto stA = [&](int buf, int h, int kt) {
        g2l16(abase + goff0 + (size_t)h * ghalf + (size_t)kt * 64,
              lds + buf * 24576 + h * 8192 + P);
    };
    auto stB = [&](int buf, int kt) {
        g2l16(bbase + goff0 + (size_t)kt * 64,
              lds + buf * 24576 + 16384 + P);
    };

    // prologue: tiles 0,1 staged (3 instr each); wait tile0 (tile1's 3 in flight)
    stA(0, 0, 0); stA(0, 1, 0); stB(0, 0);
    stA(1, 0, 1); stA(1, 1, 1); stB(1, 1);
    asm volatile("s_waitcnt vmcnt(3)" ::: "memory");
    __builtin_amdgcn_s_barrier();
    __builtin_amdgcn_sched_barrier(0);

    const int NT = kloop >> 5;
    for (int kt = 0; kt < NT; ++kt) {
        const char* lb = lds + (kt % 3) * 24576;
        const int nbuf = (kt + 2) % 3;
        const bool pre = (kt + 2) < NT;

        bf16x8 bfr[2], afr[4];
#pragma unroll
        for (int nf = 0; nf < 2; ++nf)
            bfr[nf] = *reinterpret_cast<const bf16x8*>(lb + nf * 1024 + boff);
#pragma unroll
        for (int i = 0; i < 4; ++i)
            afr[i] = *reinterpret_cast<const bf16x8*>(lb + i * 1024 + aoff);
        if (pre) { stA(nbuf, 0, kt + 2); stA(nbuf, 1, kt + 2); }
        asm volatile("s_waitcnt lgkmcnt(0)");
        __builtin_amdgcn_s_setprio(1);
#pragma unroll
        for (int i = 0; i < 4; ++i)
#pragma unroll
            for (int nf = 0; nf < 2; ++nf)
                acc[i][nf] = __builtin_amdgcn_mfma_f32_16x16x32_bf16(afr[i], bfr[nf], acc[i][nf], 0, 0, 0);
        __builtin_amdgcn_s_setprio(0);

#pragma unroll
        for (int i = 0; i < 4; ++i)
            afr[i] = *reinterpret_cast<const bf16x8*>(lb + (4 + i) * 1024 + aoff);
        if (pre) stB(nbuf, kt + 2);
        asm volatile("s_waitcnt lgkmcnt(0)");
        __builtin_amdgcn_s_setprio(1);
#pragma unroll
        for (int i = 0; i < 4; ++i)
#pragma unroll
            for (int nf = 0; nf < 2; ++nf)
                acc[4 + i][nf] = __builtin_amdgcn_mfma_f32_16x16x32_bf16(afr[i], bfr[nf], acc[4 + i][nf], 0, 0, 0);
        __builtin_amdgcn_s_setprio(0);

        if (pre) {
            asm volatile("s_waitcnt vmcnt(3)" ::: "memory");   // tile kt+1 landed
        } else if (kt + 1 < NT) {
            asm volatile("s_waitcnt vmcnt(0)" ::: "memory");
        }
        if (kt + 1 < NT) {
            __builtin_amdgcn_s_barrier();
            __builtin_amdgcn_sched_barrier(0);
        }
    }

    const int gm0 = (bm << 8) + wr * 128;
    const int gn0 = (bn << 7) + wc * 32;
#pragma unroll
    for (int mf = 0; mf < 8; ++mf) {
#pragma unroll
        for (int nf = 0; nf < 2; ++nf) {
            const int gnc = gn0 + nf * 16 + rlo;
#pragma unroll
            for (int r = 0; r < 4; ++r) {
                const int gmr = gm0 + mf * 16 + g * 4 + r;
                float val = acc[mf][nf][r];
                if constexpr (EPI == 0) {
                    int t = gnc >> 10;
                    const float* bp = (t == 0) ? bias0 : ((t == 1) ? bias1 : bias2);
                    val += bp[gnc & 1023];
                    bf16* dst = (t == 0) ? q_o : ((t == 1) ? k_o : v_o);
                    int hh = (gnc >> 7) & 7, d = gnc & 127;
                    int bb = gmr >> 7, s = gmr & 127;
                    size_t idx = (t == 2)
                        ? ((((size_t)bb * 8 + hh) * 128 + d) * 128 + s)   // V stored transposed
                        : ((((size_t)bb * 8 + hh) * 128 + s) * 128 + d);
                    dst[idx] = __float2bfloat16(val);
                } else if constexpr (EPI == 1) {
                    val = fmaxf(val + bias0[gnc], 0.f);
                    ((bf16*)outp)[(size_t)gmr * N + gnc] = __float2bfloat16(val);
                } else {
                    float* pp = (float*)outp + (size_t)slice * 8388608;
                    pp[(size_t)gmr * N + gnc] = val;
                }
            }
        }
    }
}

// ---------------- GEMM: C = A @ B^T, 128^2 tile (kept for Wo, N=1024) ----------------
template<int EPI>
__global__ __launch_bounds__(256, 2)
void gemm_bt(const bf16* __restrict__ A, const bf16* __restrict__ Bm,
             int M, int N, int K,
             const float* __restrict__ bias0, const float* __restrict__ resid,
             void* __restrict__ outp) {
    (void)M;
    __shared__ __align__(16) char As[8192];
    __shared__ __align__(16) char Bs[8192];
    int tid = threadIdx.x, wave = tid >> 6, lane = tid & 63;
    int nbn = N >> 7;
    int bm = blockIdx.x / nbn, bn = blockIdx.x % nbn;
    int wm = (wave >> 1) << 6, wn = (wave & 1) << 6;
    int rlo = lane & 15, g = lane >> 4;

    const char* abase = (const char*)(A + (size_t)(bm << 7) * K);
    const char* bbase = (const char*)(Bm + (size_t)(bn << 7) * K);

    const f32x4 fzero = {0.f, 0.f, 0.f, 0.f};
    f32x4 acc[4][4];
#pragma unroll
    for (int i = 0; i < 4; ++i)
#pragma unroll
        for (int j = 0; j < 4; ++j) acc[i][j] = fzero;

    int L0 = wave * 2048 + lane * 16;
    size_t ldbyte = (size_t)K * 2;

    for (int k0 = 0; k0 < K; k0 += 32) {
#pragma unroll
        for (int j = 0; j < 2; ++j) {
            int L = L0 + j * 1024;
            int row = L >> 6;
            int cb = (L & 63) ^ (((row >> 1) & 3) << 4);
            g2l16(abase + (size_t)row * ldbyte + (size_t)k0 * 2 + cb, As + wave * 2048 + j * 1024);
            g2l16(bbase + (size_t)row * ldbyte + (size_t)k0 * 2 + cb, Bs + wave * 2048 + j * 1024);
        }
        __syncthreads();
        bf16x8 af[4], bf8[4];
#pragma unroll
        for (int i = 0; i < 4; ++i) {
            int ra = wm + i * 16 + rlo;
            af[i] = *reinterpret_cast<const bf16x8*>(As + ra * 64 + ((g * 16) ^ (((ra >> 1) & 3) << 4)));
            int rb = wn + i * 16 + rlo;
            bf8[i] = *reinterpret_cast<const bf16x8*>(Bs + rb * 64 + ((g * 16) ^ (((rb >> 1) & 3) << 4)));
        }
#pragma unroll
        for (int mi = 0; mi < 4; ++mi)
#pragma unroll
            for (int ni = 0; ni < 4; ++ni)
                acc[mi][ni] = __builtin_amdgcn_mfma_f32_16x16x32_bf16(af[mi], bf8[ni], acc[mi][ni], 0, 0, 0);
        __syncthreads();
    }

    int gm0 = (bm << 7) + wm, gn0 = (bn << 7) + wn;
#pragma unroll
    for (int mi = 0; mi < 4; ++mi) {
#pragma unroll
        for (int ni = 0; ni < 4; ++ni) {
            int gnc = gn0 + ni * 16 + rlo;
#pragma unroll
            for (int r = 0; r < 4; ++r) {
                int gmr = gm0 + mi * 16 + g * 4 + r;
                float val = acc[mi][ni][r];
                val += bias0[gnc] + resid[(size_t)gmr * N + gnc];
                ((float*)outp)[(size_t)gmr * N + gnc] = val;
            }
        }
    }
}

// ---------------- fused attention per (b,h): CTX = (softmax(QK^T/s) @ V) @ V ----------------
__global__ __launch_bounds__(256, 1)
void attn_fused(const bf16* __restrict__ Q, const bf16* __restrict__ K,
                const bf16* __restrict__ VT, bf16* __restrict__ CTX) {
    __shared__ __align__(16) char Qs[32768];
    __shared__ __align__(16) char Ks[32768];
    __shared__ __align__(16) char Vs[32768];
    int bh = blockIdx.x, b = bh >> 3, h = bh & 7;
    int tid = threadIdx.x, wave = tid >> 6, lane = tid & 63;
    const char* qsrc = (const char*)(Q + (size_t)bh * 16384);
    const char* ksrc = (const char*)(K + (size_t)bh * 16384);
    const char* vsrc = (const char*)(VT + (size_t)bh * 16384);
#pragma unroll
    for (int j = 0; j < 8; ++j) {
        int L = wave * 8192 + j * 1024 + lane * 16;
        int row = L >> 8;
        int cb = (L & 255) ^ ((row & 7) << 4);
        g2l16(qsrc + row * 256 + cb, Qs + wave * 8192 + j * 1024);
        g2l16(ksrc + row * 256 + cb, Ks + wave * 8192 + j * 1024);
        g2l16(vsrc + row * 256 + cb, Vs + wave * 8192 + j * 1024);
    }
    __syncthreads();
    int rlo = lane & 15, g = lane >> 4;
    const f32x4 fzero = {0.f, 0.f, 0.f, 0.f};

    f32x4 acc[2][8];
#pragma unroll
    for (int mi = 0; mi < 2; ++mi)
#pragma unroll
        for (int ni = 0; ni < 8; ++ni) acc[mi][ni] = fzero;
#pragma unroll
    for (int kk = 0; kk < 4; ++kk) {
        bf16x8 aq[2], bk8[8];
#pragma unroll
        for (int mi = 0; mi < 2; ++mi) {
            int row = wave * 32 + mi * 16 + rlo;
            aq[mi] = *reinterpret_cast<const bf16x8*>(Qs + row * 256 + ((kk * 64 + g * 16) ^ ((row & 7) << 4)));
        }
#pragma unroll
        for (int ni = 0; ni < 8; ++ni) {
            int row = ni * 16 + rlo;
            bk8[ni] = *reinterpret_cast<const bf16x8*>(Ks + row * 256 + ((kk * 64 + g * 16) ^ ((row & 7) << 4)));
        }
#pragma unroll
        for (int mi = 0; mi < 2; ++mi)
#pragma unroll
            for (int ni = 0; ni < 8; ++ni)
                acc[mi][ni] = __builtin_amdgcn_mfma_f32_16x16x32_bf16(aq[mi], bk8[ni], acc[mi][ni], 0, 0, 0);
    }

    const float scale = 0.088388347648318447f;  // 1/sqrt(128)
#pragma unroll
    for (int mi = 0; mi < 2; ++mi) {
#pragma unroll
        for (int r = 0; r < 4; ++r) {
            float m = -3e38f;
#pragma unroll
            for (int ni = 0; ni < 8; ++ni) m = fmaxf(m, acc[mi][ni][r]);
#pragma unroll
            for (int o = 1; o < 16; o <<= 1) m = fmaxf(m, __shfl_xor(m, o));
            m *= scale;
            float e[8];
            float sum = 0.f;
#pragma unroll
            for (int ni = 0; ni < 8; ++ni) { e[ni] = __expf(acc[mi][ni][r] * scale - m); sum += e[ni]; }
#pragma unroll
            for (int o = 1; o < 16; o <<= 1) sum += __shfl_xor(sum, o);
            float inv = 1.f / sum;
            int qrow = wave * 32 + mi * 16 + g * 4 + r;
#pragma unroll
            for (int ni = 0; ni < 8; ++ni) {
                int cbyte = ((ni * 16 + rlo) * 2) ^ ((qrow & 7) << 4);
                *(unsigned short*)(Qs + qrow * 256 + cbyte) = bfbits(e[ni] * inv);
            }
        }
    }
    __syncthreads();

    f32x4 accT[2][8];
#pragma unroll
    for (int mi = 0; mi < 2; ++mi)
#pragma unroll
        for (int ni = 0; ni < 8; ++ni) accT[mi][ni] = fzero;
#pragma unroll
    for (int kk = 0; kk < 4; ++kk) {
        bf16x8 ap[2], bv8[8];
#pragma unroll
        for (int mi = 0; mi < 2; ++mi) {
            int row = wave * 32 + mi * 16 + rlo;
            ap[mi] = *reinterpret_cast<const bf16x8*>(Qs + row * 256 + ((kk * 64 + g * 16) ^ ((row & 7) << 4)));
        }
#pragma unroll
        for (int ni = 0; ni < 8; ++ni) {
            int row = ni * 16 + rlo;
            bv8[ni] = *reinterpret_cast<const bf16x8*>(Vs + row * 256 + ((kk * 64 + g * 16) ^ ((row & 7) << 4)));
        }
#pragma unroll
        for (int mi = 0; mi < 2; ++mi)
#pragma unroll
            for (int ni = 0; ni < 8; ++ni)
                accT[mi][ni] = __builtin_amdgcn_mfma_f32_16x16x32_bf16(ap[mi], bv8[ni], accT[mi][ni], 0, 0, 0);
    }
#pragma unroll
    for (int mi = 0; mi < 2; ++mi)
#pragma unroll
        for (int ni = 0; ni < 8; ++ni)
#pragma unroll
            for (int r = 0; r < 4; ++r) {
                int trow = wave * 32 + mi * 16 + g * 4 + r;
                int cbyte = ((ni * 16 + rlo) * 2) ^ ((trow & 7) << 4);
                *(unsigned short*)(Ks + trow * 256 + cbyte) = bfbits(accT[mi][ni][r]);
            }
    __syncthreads();

    f32x4 accC[2][8];
#pragma unroll
    for (int mi = 0; mi < 2; ++mi)
#pragma unroll
        for (int ni = 0; ni < 8; ++ni) accC[mi][ni] = fzero;
#pragma unroll
    for (int kk = 0; kk < 4; ++kk) {
        bf16x8 at[2], bv8[8];
#pragma unroll
        for (int mi = 0; mi < 2; ++mi) {
            int row = wave * 32 + mi * 16 + rlo;
            at[mi] = *reinterpret_cast<const bf16x8*>(Ks + row * 256 + ((kk * 64 + g * 16) ^ ((row & 7) << 4)));
        }
#pragma unroll
        for (int ni = 0; ni < 8; ++ni) {
            int row = ni * 16 + rlo;
            bv8[ni] = *reinterpret_cast<const bf16x8*>(Vs + row * 256 + ((kk * 64 + g * 16) ^ ((row & 7) << 4)));
        }
#pragma unroll
        for (int mi = 0; mi < 2; ++mi)
#pragma unroll
            for (int ni = 0; ni < 8; ++ni)
                accC[mi][ni] = __builtin_amdgcn_mfma_f32_16x16x32_bf16(at[mi], bv8[ni], accC[mi][ni], 0, 0, 0);
    }
    unsigned short* cdst = (unsigned short*)CTX;
#pragma unroll
    for (int mi = 0; mi < 2; ++mi)
#pragma unroll
        for (int ni = 0; ni < 8; ++ni)
#pragma unroll
            for (int r = 0; r < 4; ++r) {
                int q = wave * 32 + mi * 16 + g * 4 + r;
                int gm = b * 128 + q;
                int col = h * 128 + ni * 16 + rlo;
                cdst[(size_t)gm * 1024 + col] = bfbits(accC[mi][ni][r]);
            }
}

// ---------------- layernorm over rows of 1024 f32 ----------------
template<int MODE>
__global__ __launch_bounds__(256)
void ln_k(const float* __restrict__ Y, const float* __restrict__ w, const float* __restrict__ b,
          float* __restrict__ Hf, bf16* __restrict__ Hb) {
    int row = blockIdx.x, tid = threadIdx.x;
    float4 v = reinterpret_cast<const float4*>(Y + (size_t)row * 1024)[tid];
    float s = v.x + v.y + v.z + v.w;
    float q = v.x * v.x + v.y * v.y + v.z * v.z + v.w * v.w;
#pragma unroll
    for (int o = 1; o < 64; o <<= 1) { s += __shfl_xor(s, o); q += __shfl_xor(q, o); }
    __shared__ float ss[4], sq[4];
    if ((tid & 63) == 0) { ss[tid >> 6] = s; sq[tid >> 6] = q; }
    __syncthreads();
    s = ss[0] + ss[1] + ss[2] + ss[3];
    q = sq[0] + sq[1] + sq[2] + sq[3];
    float u = s * (1.f / 1024.f);
    float var = fmaxf(q * (1.f / 1024.f) - u * u, 0.f);
    float rstd = rsqrtf(var + 1e-12f);
    float4 wv = reinterpret_cast<const float4*>(w)[tid];
    float4 bv = reinterpret_cast<const float4*>(b)[tid];
    float o0 = wv.x * (v.x - u) * rstd + bv.x;
    float o1 = wv.y * (v.y - u) * rstd + bv.y;
    float o2 = wv.z * (v.z - u) * rstd + bv.z;
    float o3 = wv.w * (v.w - u) * rstd + bv.w;
    reinterpret_cast<float4*>(Hf + (size_t)row * 1024)[tid] = make_float4(o0, o1, o2, o3);
    if constexpr (MODE == 0) {
        ushort4 ob;
        ob.x = bfbits(o0); ob.y = bfbits(o1); ob.z = bfbits(o2); ob.w = bfbits(o3);
        reinterpret_cast<ushort4*>(Hb)[row * 256 + tid] = ob;
    }
}

// ---- final LN: y = LN(PA + PB + b3 + resid), write f32 out ----
__global__ __launch_bounds__(256)
void ln2k(const float* __restrict__ PA, const float* __restrict__ PB,
          const float* __restrict__ b3, const float* __restrict__ resid,
          const float* __restrict__ w, const float* __restrict__ b,
          float* __restrict__ out) {
    int row = blockIdx.x, tid = threadIdx.x;
    size_t off = (size_t)row * 256 + tid;
    float4 pa = reinterpret_cast<const float4*>(PA)[off];
    float4 pb = reinterpret_cast<const float4*>(PB)[off];
    float4 bi = reinterpret_cast<const float4*>(b3)[tid];
    float4 rs = reinterpret_cast<const float4*>(resid)[off];
    float4 v = make_float4(pa.x + pb.x + bi.x + rs.x, pa.y + pb.y + bi.y + rs.y,
                           pa.z + pb.z + bi.z + rs.z, pa.w + pb.w + bi.w + rs.w);
    float s = v.x + v.y + v.z + v.w;
    float q = v.x * v.x + v.y * v.y + v.z * v.z + v.w * v.w;
#pragma unroll
    for (int o = 1; o < 64; o <<= 1) { s += __shfl_xor(s, o); q += __shfl_xor(q, o); }
    __shared__ float ss[4], sq[4];
    if ((tid & 63) == 0) { ss[tid >> 6] = s; sq[tid >> 6] = q; }
    __syncthreads();
    s = ss[0] + ss[1] + ss[2] + ss[3];
    q = sq[0] + sq[1] + sq[2] + sq[3];
    float u = s * (1.f / 1024.f);
    float var = fmaxf(q * (1.f / 1024.f) - u * u, 0.f);
    float rstd = rsqrtf(var + 1e-12f);
    float4 wv = reinterpret_cast<const float4*>(w)[tid];
    float4 bv = reinterpret_cast<const float4*>(b)[tid];
    float4 o4;
    o4.x = wv.x * (v.x - u) * rstd + bv.x;
    o4.y = wv.y * (v.y - u) * rstd + bv.y;
    o4.z = wv.z * (v.z - u) * rstd + bv.z;
    o4.w = wv.w * (v.w - u) * rstd + bv.w;
    reinterpret_cast<float4*>(out)[off] = o4;
}

extern "C" void kernel_launch(void* const* d_in, const int* in_sizes, int n_in,
                              void* d_out, int out_size, void* d_ws, size_t ws_size,
                              hipStream_t stream) {
    (void)in_sizes; (void)n_in; (void)out_size; (void)ws_size;
    const float* x    = (const float*)d_in[0];
    const float* Wq   = (const float*)d_in[2];
    const float* bq   = (const float*)d_in[3];
    const float* Wk   = (const float*)d_in[4];
    const float* bk   = (const float*)d_in[5];
    const float* Wv   = (const float*)d_in[6];
    const float* bv   = (const float*)d_in[7];
    const float* Wo   = (const float*)d_in[8];
    const float* bo   = (const float*)d_in[9];
    const float* ln1w = (const float*)d_in[10];
    const float* ln1b = (const float*)d_in[11];
    const float* W1   = (const float*)d_in[12];
    const float* b1   = (const float*)d_in[13];
    const float* W2   = (const float*)d_in[14];
    const float* b2   = (const float*)d_in[15];
    const float* W3   = (const float*)d_in[16];
    const float* b3   = (const float*)d_in[17];
    const float* ln2w = (const float*)d_in[18];
    const float* ln2b = (const float*)d_in[19];

    char* ws = (char*)d_ws;
    bf16*  XB    = (bf16*)(ws + 0);
    bf16*  WQKVB = (bf16*)(ws + 16777216);
    bf16*  WOB   = (bf16*)(ws + 23068672);
    bf16*  W1B   = (bf16*)(ws + 25165824);
    bf16*  W2B   = (bf16*)(ws + 29360128);
    bf16*  W3B   = (bf16*)(ws + 46137344);
    bf16*  Qb    = (bf16*)(ws + 54525952);
    bf16*  Kb    = (bf16*)(ws + 71303168);
    bf16*  VTb   = (bf16*)(ws + 88080384);    // [B,H,DK,S] (written transposed by QKV epi)
    bf16*  CTX   = (bf16*)(ws + 138412032);
    float* Y2    = (float*)(ws + 155189248);
    float* H32   = (float*)(ws + 188743680);
    bf16*  HB    = (bf16*)(ws + 222298112);
    bf16*  F1    = (bf16*)(ws + 155189248);   // overlays Y2 (dead after LN1)
    bf16*  F2    = (bf16*)(ws + 54525952);    // overlays Qb..VTb (dead after attn)
    float* PW3   = (float*)(ws + 121634816);  // 67 MB span; clobbers CTX/Y2 (dead by W3)

    CastArgs ca;
    ca.src[0] = x;  ca.src[1] = Wq; ca.src[2] = Wk; ca.src[3] = Wv;
    ca.src[4] = Wo; ca.src[5] = W1; ca.src[6] = W2; ca.src[7] = W3;
    ca.end[0] = 2097152; ca.end[1] = 2359296; ca.end[2] = 2621440; ca.end[3] = 2883584;
    ca.end[4] = 3145728; ca.end[5] = 3670016; ca.end[6] = 5767168; ca.end[7] = 6815744;
    castall<<<2048, 256, 0, stream>>>(ca, (ushort4*)ws);

    // QKV: [8192,1024] @ [3072,1024]^T -> Q,K [B,H,S,DK], V -> VT [B,H,DK,S]
    gemm256<0, 0><<<768, 512, 0, stream>>>(XB, WQKVB, 3072, 1024, 1024,
                                           bq, bk, bv, nullptr, Qb, Kb, VTb);
    attn_fused<<<512, 256, 0, stream>>>(Qb, Kb, VTb, CTX);
    // attn_out + x -> Y2 (f32)
    gemm_bt<2><<<512, 256, 0, stream>>>(CTX, WOB, 8192, 1024, 1024, bo, x, (void*)Y2);
    ln_k<0><<<8192, 256, 0, stream>>>(Y2, ln1w, ln1b, H32, HB);
    // MLP
    gemm256<1, 0><<<512, 512, 0, stream>>>(HB, W1B, 2048, 1024, 1024,
                                           b1, nullptr, nullptr, (void*)F1, nullptr, nullptr, nullptr);
    gemm256<1, 0><<<1024, 512, 0, stream>>>(F1, W2B, 4096, 2048, 2048,
                                            b2, nullptr, nullptr, (void*)F2, nullptr, nullptr, nullptr);
    // W3 split-K=2 -> f32 partials; reduce+bias+resid+LN fused in ln2k
    gemm256<2, 1><<<512, 512, 0, stream>>>(F2, W3B, 1024, 4096, 2048,
                                           nullptr, nullptr, nullptr, (void*)PW3, nullptr, nullptr, nullptr);
    ln2k<<<8192, 256, 0, stream>>>(PW3, PW3 + 8388608, b3, H32, ln2w, ln2b, (float*)d_out);
}

// Round 11
// 442.882 us; speedup vs baseline: 1.0509x; 1.0509x over previous
//
#include <hip/hip_runtime.h>
#include <hip/hip_bf16.h>

using bf16 = __hip_bfloat16;
typedef __attribute__((ext_vector_type(4))) float f32x4;
typedef __attribute__((ext_vector_type(8))) short bf16x8;

__device__ __forceinline__ unsigned short bfbits(float f) {
    bf16 h = __float2bfloat16(f);
    return __builtin_bit_cast(unsigned short, h);
}

__device__ __forceinline__ void g2l16(const void* g, void* l) {
    __builtin_amdgcn_global_load_lds(
        (const __attribute__((address_space(1))) unsigned int*)g,
        (__attribute__((address_space(3))) unsigned int*)l, 16, 0, 0);
}

// ---------------- fused cast f32 -> bf16 for all 8 tensors (1 launch) ----------------
struct CastArgs {
    const float* src[8];
    int end[8];   // prefix ends in float4 units; end[7] = 6815744
};
__global__ __launch_bounds__(256)
void castall(CastArgs a, ushort4* __restrict__ out) {
    int stride = gridDim.x * blockDim.x;
    for (int i = blockIdx.x * blockDim.x + threadIdx.x; i < 6815744; i += stride) {
        const float* sp; int beg;
        if      (i < a.end[0]) { sp = a.src[0]; beg = 0; }
        else if (i < a.end[1]) { sp = a.src[1]; beg = a.end[0]; }
        else if (i < a.end[2]) { sp = a.src[2]; beg = a.end[1]; }
        else if (i < a.end[3]) { sp = a.src[3]; beg = a.end[2]; }
        else if (i < a.end[4]) { sp = a.src[4]; beg = a.end[3]; }
        else if (i < a.end[5]) { sp = a.src[5]; beg = a.end[4]; }
        else if (i < a.end[6]) { sp = a.src[6]; beg = a.end[5]; }
        else                   { sp = a.src[7]; beg = a.end[6]; }
        float4 v = reinterpret_cast<const float4*>(sp)[i - beg];
        ushort4 o;
        o.x = bfbits(v.x); o.y = bfbits(v.y); o.z = bfbits(v.z); o.w = bfbits(v.w);
        out[i] = o;
    }
}

// ======= 256x256-tile 8-wave GEMM: ring-3, compiler-minimal lgkm waits =======
// C = A @ B^T. A:[M,ldk] bf16 rm; Bm:[N,ldk] bf16 rm. BK=32, 96KB LDS ring of 3,
// staged 2 K-tiles ahead, counted vmcnt(4), 1 barrier / K-tile.
// Change vs R4/R9: all 12 ds_reads issued up-front, NO explicit lgkmcnt before the
// MFMA clusters (compiler emits minimal per-operand counts -> waves start MFMA as
// soon as THEIR reads land, staggering LDS-pipe service under other SIMDs' MFMAs).
// One lgkmcnt(0) after MFMAs closes the cross-wave WAR on the ring buffer before
// the barrier (free: MFMA consumption already drained the queue).
// EPI 0: QKV scatter (+per-tensor bias); Q,K -> [B,H,S,DK], V -> [B,H,DK,S] transposed
// EPI 1: relu(acc+bias) -> bf16 [M,N]
// EPI 2: raw f32 acc -> outp + slice*M*N  (split-K partials)
template<int EPI, int SPLITK>
__global__ __launch_bounds__(512, 2)
void gemm256(const bf16* __restrict__ A, const bf16* __restrict__ Bm,
             int N, int ldk, int kloop,
             const float* __restrict__ bias0, const float* __restrict__ bias1,
             const float* __restrict__ bias2,
             void* __restrict__ outp,
             bf16* __restrict__ q_o, bf16* __restrict__ k_o, bf16* __restrict__ v_o) {
    __shared__ __align__(16) char lds[98304];
    const int tid = threadIdx.x;
    const int lane = tid & 63, wave = tid >> 6;
    const int rlo = lane & 15, g = lane >> 4;
    const int wr = wave >> 2, wc = wave & 3;
    const int nbn = N >> 8;
    const int nwg = gridDim.x;
    int wg = (int)blockIdx.x;
    wg = (wg & 7) * (nwg >> 3) + (wg >> 3);   // XCD swizzle (nwg % 8 == 0)
    int slice = 0;
    if constexpr (SPLITK) {
        int half = nwg >> 1;
        slice = (wg >= half) ? 1 : 0;
        wg -= slice * half;
    }
    const int bm = wg / nbn, bn = wg % nbn;
    const size_t ldb = (size_t)ldk * 2;
    const char* abase = (const char*)A + ((size_t)bm << 8) * ldb + (size_t)slice * kloop * 2;
    const char* bbase = (const char*)Bm + ((size_t)bn << 8) * ldb + (size_t)slice * kloop * 2;

    const int P = tid * 16;
    const int R = P >> 7;
    const int qs = (P & 127) ^ ((R & 7) << 4);          // unswizzle
    const size_t goff0 = (size_t)(R * 2 + (qs >> 6)) * ldb + (qs & 63);
    const size_t ghalf = (size_t)128 * ldb;

    const int o_in = (((rlo & 1) << 6) | (g << 4)) ^ (((rlo >> 1) & 7) << 4);
    const int aoff = wr * 8192 + (rlo >> 1) * 128 + o_in;
    const int boff = 16384 + (wc >> 1) * 8192 + (wc & 1) * 4096 + (rlo >> 1) * 128 + o_in;

    const f32x4 fz = {0.f, 0.f, 0.f, 0.f};
    f32x4 acc[8][4];
#pragma unroll
    for (int i = 0; i < 8; ++i)
#pragma unroll
        for (int j = 0; j < 4; ++j) acc[i][j] = fz;

    auto stA = [&](int buf, int h, int kt) {
        g2l16(abase + goff0 + (size_t)h * ghalf + (size_t)kt * 64,
              lds + buf * 32768 + h * 8192 + P);
    };
    auto stB = [&](int buf, int h, int kt) {
        g2l16(bbase + goff0 + (size_t)h * ghalf + (size_t)kt * 64,
              lds + buf * 32768 + 16384 + h * 8192 + P);
    };

    // prologue: tiles 0,1 staged; wait tile0 (tile1's 4 stay in flight)
    stA(0, 0, 0); stA(0, 1, 0); stB(0, 0, 0); stB(0, 1, 0);
    stA(1, 0, 1); stA(1, 1, 1); stB(1, 0, 1); stB(1, 1, 1);
    asm volatile("s_waitcnt vmcnt(4)" ::: "memory");
    __builtin_amdgcn_s_barrier();
    __builtin_amdgcn_sched_barrier(0);

    const int NT = kloop >> 5;
    for (int kt = 0; kt < NT; ++kt) {
        const char* lb = lds + (kt % 3) * 32768;
        const int nbuf = (kt + 2) % 3;
        const bool pre = (kt + 2) < NT;

        // all 12 ds_reads up-front; compiler inserts minimal lgkm counts at uses
        bf16x8 bfr[4], afr[8];
#pragma unroll
        for (int nf = 0; nf < 4; ++nf)
            bfr[nf] = *reinterpret_cast<const bf16x8*>(lb + nf * 1024 + boff);
#pragma unroll
        for (int i = 0; i < 8; ++i)
            afr[i] = *reinterpret_cast<const bf16x8*>(lb + i * 1024 + aoff);
        if (pre) { stA(nbuf, 0, kt + 2); stA(nbuf, 1, kt + 2);
                   stB(nbuf, 0, kt + 2); stB(nbuf, 1, kt + 2); }

        __builtin_amdgcn_s_setprio(1);
#pragma unroll
        for (int i = 0; i < 4; ++i)
#pragma unroll
            for (int nf = 0; nf < 4; ++nf)
                acc[i][nf] = __builtin_amdgcn_mfma_f32_16x16x32_bf16(afr[i], bfr[nf], acc[i][nf], 0, 0, 0);
#pragma unroll
        for (int i = 0; i < 4; ++i)
#pragma unroll
            for (int nf = 0; nf < 4; ++nf)
                acc[4 + i][nf] = __builtin_amdgcn_mfma_f32_16x16x32_bf16(afr[4 + i], bfr[nf], acc[4 + i][nf], 0, 0, 0);
        __builtin_amdgcn_s_setprio(0);

        // close WAR on this ring buffer before the barrier (reads all consumed -> free)
        asm volatile("s_waitcnt lgkmcnt(0)" ::: "memory");
        if (pre) {
            asm volatile("s_waitcnt vmcnt(4)" ::: "memory");   // tile kt+1 landed
        } else if (kt + 1 < NT) {
            asm volatile("s_waitcnt vmcnt(0)" ::: "memory");
        }
        if (kt + 1 < NT) {
            __builtin_amdgcn_s_barrier();
            __builtin_amdgcn_sched_barrier(0);
        }
    }

    const int gm0 = (bm << 8) + wr * 128;
    const int gn0 = (bn << 8) + wc * 64;
#pragma unroll
    for (int mf = 0; mf < 8; ++mf) {
#pragma unroll
        for (int nf = 0; nf < 4; ++nf) {
            const int gnc = gn0 + nf * 16 + rlo;
#pragma unroll
            for (int r = 0; r < 4; ++r) {
                const int gmr = gm0 + mf * 16 + g * 4 + r;
                float val = acc[mf][nf][r];
                if constexpr (EPI == 0) {
                    int t = gnc >> 10;
                    const float* bp = (t == 0) ? bias0 : ((t == 1) ? bias1 : bias2);
                    val += bp[gnc & 1023];
                    bf16* dst = (t == 0) ? q_o : ((t == 1) ? k_o : v_o);
                    int hh = (gnc >> 7) & 7, d = gnc & 127;
                    int bb = gmr >> 7, s = gmr & 127;
                    size_t idx = (t == 2)
                        ? ((((size_t)bb * 8 + hh) * 128 + d) * 128 + s)   // V stored transposed
                        : ((((size_t)bb * 8 + hh) * 128 + s) * 128 + d);
                    dst[idx] = __float2bfloat16(val);
                } else if constexpr (EPI == 1) {
                    val = fmaxf(val + bias0[gnc], 0.f);
                    ((bf16*)outp)[(size_t)gmr * N + gnc] = __float2bfloat16(val);
                } else {
                    float* pp = (float*)outp + (size_t)slice * 8388608;
                    pp[(size_t)gmr * N + gnc] = val;
                }
            }
        }
    }
}

// ---------------- GEMM: C = A @ B^T, 128^2 tile (kept for Wo, N=1024) ----------------
template<int EPI>
__global__ __launch_bounds__(256, 2)
void gemm_bt(const bf16* __restrict__ A, const bf16* __restrict__ Bm,
             int M, int N, int K,
             const float* __restrict__ bias0, const float* __restrict__ resid,
             void* __restrict__ outp) {
    (void)M;
    __shared__ __align__(16) char As[8192];
    __shared__ __align__(16) char Bs[8192];
    int tid = threadIdx.x, wave = tid >> 6, lane = tid & 63;
    int nbn = N >> 7;
    int bm = blockIdx.x / nbn, bn = blockIdx.x % nbn;
    int wm = (wave >> 1) << 6, wn = (wave & 1) << 6;
    int rlo = lane & 15, g = lane >> 4;

    const char* abase = (const char*)(A + (size_t)(bm << 7) * K);
    const char* bbase = (const char*)(Bm + (size_t)(bn << 7) * K);

    const f32x4 fzero = {0.f, 0.f, 0.f, 0.f};
    f32x4 acc[4][4];
#pragma unroll
    for (int i = 0; i < 4; ++i)
#pragma unroll
        for (int j = 0; j < 4; ++j) acc[i][j] = fzero;

    int L0 = wave * 2048 + lane * 16;
    size_t ldbyte = (size_t)K * 2;

    for (int k0 = 0; k0 < K; k0 += 32) {
#pragma unroll
        for (int j = 0; j < 2; ++j) {
            int L = L0 + j * 1024;
            int row = L >> 6;
            int cb = (L & 63) ^ (((row >> 1) & 3) << 4);
            g2l16(abase + (size_t)row * ldbyte + (size_t)k0 * 2 + cb, As + wave * 2048 + j * 1024);
            g2l16(bbase + (size_t)row * ldbyte + (size_t)k0 * 2 + cb, Bs + wave * 2048 + j * 1024);
        }
        __syncthreads();
        bf16x8 af[4], bf8[4];
#pragma unroll
        for (int i = 0; i < 4; ++i) {
            int ra = wm + i * 16 + rlo;
            af[i] = *reinterpret_cast<const bf16x8*>(As + ra * 64 + ((g * 16) ^ (((ra >> 1) & 3) << 4)));
            int rb = wn + i * 16 + rlo;
            bf8[i] = *reinterpret_cast<const bf16x8*>(Bs + rb * 64 + ((g * 16) ^ (((rb >> 1) & 3) << 4)));
        }
#pragma unroll
        for (int mi = 0; mi < 4; ++mi)
#pragma unroll
            for (int ni = 0; ni < 4; ++ni)
                acc[mi][ni] = __builtin_amdgcn_mfma_f32_16x16x32_bf16(af[mi], bf8[ni], acc[mi][ni], 0, 0, 0);
        __syncthreads();
    }

    int gm0 = (bm << 7) + wm, gn0 = (bn << 7) + wn;
#pragma unroll
    for (int mi = 0; mi < 4; ++mi) {
#pragma unroll
        for (int ni = 0; ni < 4; ++ni) {
            int gnc = gn0 + ni * 16 + rlo;
#pragma unroll
            for (int r = 0; r < 4; ++r) {
                int gmr = gm0 + mi * 16 + g * 4 + r;
                float val = acc[mi][ni][r];
                val += bias0[gnc] + resid[(size_t)gmr * N + gnc];
                ((float*)outp)[(size_t)gmr * N + gnc] = val;
            }
        }
    }
}

// ---------------- fused attention per (b,h): CTX = (softmax(QK^T/s) @ V) @ V ----------------
__global__ __launch_bounds__(256, 1)
void attn_fused(const bf16* __restrict__ Q, const bf16* __restrict__ K,
                const bf16* __restrict__ VT, bf16* __restrict__ CTX) {
    __shared__ __align__(16) char Qs[32768];
    __shared__ __align__(16) char Ks[32768];
    __shared__ __align__(16) char Vs[32768];
    int bh = blockIdx.x, b = bh >> 3, h = bh & 7;
    int tid = threadIdx.x, wave = tid >> 6, lane = tid & 63;
    const char* qsrc = (const char*)(Q + (size_t)bh * 16384);
    const char* ksrc = (const char*)(K + (size_t)bh * 16384);
    const char* vsrc = (const char*)(VT + (size_t)bh * 16384);
#pragma unroll
    for (int j = 0; j < 8; ++j) {
        int L = wave * 8192 + j * 1024 + lane * 16;
        int row = L >> 8;
        int cb = (L & 255) ^ ((row & 7) << 4);
        g2l16(qsrc + row * 256 + cb, Qs + wave * 8192 + j * 1024);
        g2l16(ksrc + row * 256 + cb, Ks + wave * 8192 + j * 1024);
        g2l16(vsrc + row * 256 + cb, Vs + wave * 8192 + j * 1024);
    }
    __syncthreads();
    int rlo = lane & 15, g = lane >> 4;
    const f32x4 fzero = {0.f, 0.f, 0.f, 0.f};

    f32x4 acc[2][8];
#pragma unroll
    for (int mi = 0; mi < 2; ++mi)
#pragma unroll
        for (int ni = 0; ni < 8; ++ni) acc[mi][ni] = fzero;
#pragma unroll
    for (int kk = 0; kk < 4; ++kk) {
        bf16x8 aq[2], bk8[8];
#pragma unroll
        for (int mi = 0; mi < 2; ++mi) {
            int row = wave * 32 + mi * 16 + rlo;
            aq[mi] = *reinterpret_cast<const bf16x8*>(Qs + row * 256 + ((kk * 64 + g * 16) ^ ((row & 7) << 4)));
        }
#pragma unroll
        for (int ni = 0; ni < 8; ++ni) {
            int row = ni * 16 + rlo;
            bk8[ni] = *reinterpret_cast<const bf16x8*>(Ks + row * 256 + ((kk * 64 + g * 16) ^ ((row & 7) << 4)));
        }
#pragma unroll
        for (int mi = 0; mi < 2; ++mi)
#pragma unroll
            for (int ni = 0; ni < 8; ++ni)
                acc[mi][ni] = __builtin_amdgcn_mfma_f32_16x16x32_bf16(aq[mi], bk8[ni], acc[mi][ni], 0, 0, 0);
    }

    const float scale = 0.088388347648318447f;  // 1/sqrt(128)
#pragma unroll
    for (int mi = 0; mi < 2; ++mi) {
#pragma unroll
        for (int r = 0; r < 4; ++r) {
            float m = -3e38f;
#pragma unroll
            for (int ni = 0; ni < 8; ++ni) m = fmaxf(m, acc[mi][ni][r]);
#pragma unroll
            for (int o = 1; o < 16; o <<= 1) m = fmaxf(m, __shfl_xor(m, o));
            m *= scale;
            float e[8];
            float sum = 0.f;
#pragma unroll
            for (int ni = 0; ni < 8; ++ni) { e[ni] = __expf(acc[mi][ni][r] * scale - m); sum += e[ni]; }
#pragma unroll
            for (int o = 1; o < 16; o <<= 1) sum += __shfl_xor(sum, o);
            float inv = 1.f / sum;
            int qrow = wave * 32 + mi * 16 + g * 4 + r;
#pragma unroll
            for (int ni = 0; ni < 8; ++ni) {
                int cbyte = ((ni * 16 + rlo) * 2) ^ ((qrow & 7) << 4);
                *(unsigned short*)(Qs + qrow * 256 + cbyte) = bfbits(e[ni] * inv);
            }
        }
    }
    __syncthreads();

    f32x4 accT[2][8];
#pragma unroll
    for (int mi = 0; mi < 2; ++mi)
#pragma unroll
        for (int ni = 0; ni < 8; ++ni) accT[mi][ni] = fzero;
#pragma unroll
    for (int kk = 0; kk < 4; ++kk) {
        bf16x8 ap[2], bv8[8];
#pragma unroll
        for (int mi = 0; mi < 2; ++mi) {
            int row = wave * 32 + mi * 16 + rlo;
            ap[mi] = *reinterpret_cast<const bf16x8*>(Qs + row * 256 + ((kk * 64 + g * 16) ^ ((row & 7) << 4)));
        }
#pragma unroll
        for (int ni = 0; ni < 8; ++ni) {
            int row = ni * 16 + rlo;
            bv8[ni] = *reinterpret_cast<const bf16x8*>(Vs + row * 256 + ((kk * 64 + g * 16) ^ ((row & 7) << 4)));
        }
#pragma unroll
        for (int mi = 0; mi < 2; ++mi)
#pragma unroll
            for (int ni = 0; ni < 8; ++ni)
                accT[mi][ni] = __builtin_amdgcn_mfma_f32_16x16x32_bf16(ap[mi], bv8[ni], accT[mi][ni], 0, 0, 0);
    }
#pragma unroll
    for (int mi = 0; mi < 2; ++mi)
#pragma unroll
        for (int ni = 0; ni < 8; ++ni)
#pragma unroll
            for (int r = 0; r < 4; ++r) {
                int trow = wave * 32 + mi * 16 + g * 4 + r;
                int cbyte = ((ni * 16 + rlo) * 2) ^ ((trow & 7) << 4);
                *(unsigned short*)(Ks + trow * 256 + cbyte) = bfbits(accT[mi][ni][r]);
            }
    __syncthreads();

    f32x4 accC[2][8];
#pragma unroll
    for (int mi = 0; mi < 2; ++mi)
#pragma unroll
        for (int ni = 0; ni < 8; ++ni) accC[mi][ni] = fzero;
#pragma unroll
    for (int kk = 0; kk < 4; ++kk) {
        bf16x8 at[2], bv8[8];
#pragma unroll
        for (int mi = 0; mi < 2; ++mi) {
            int row = wave * 32 + mi * 16 + rlo;
            at[mi] = *reinterpret_cast<const bf16x8*>(Ks + row * 256 + ((kk * 64 + g * 16) ^ ((row & 7) << 4)));
        }
#pragma unroll
        for (int ni = 0; ni < 8; ++ni) {
            int row = ni * 16 + rlo;
            bv8[ni] = *reinterpret_cast<const bf16x8*>(Vs + row * 256 + ((kk * 64 + g * 16) ^ ((row & 7) << 4)));
        }
#pragma unroll
        for (int mi = 0; mi < 2; ++mi)
#pragma unroll
            for (int ni = 0; ni < 8; ++ni)
                accC[mi][ni] = __builtin_amdgcn_mfma_f32_16x16x32_bf16(at[mi], bv8[ni], accC[mi][ni], 0, 0, 0);
    }
    unsigned short* cdst = (unsigned short*)CTX;
#pragma unroll
    for (int mi = 0; mi < 2; ++mi)
#pragma unroll
        for (int ni = 0; ni < 8; ++ni)
#pragma unroll
            for (int r = 0; r < 4; ++r) {
                int q = wave * 32 + mi * 16 + g * 4 + r;
                int gm = b * 128 + q;
                int col = h * 128 + ni * 16 + rlo;
                cdst[(size_t)gm * 1024 + col] = bfbits(accC[mi][ni][r]);
            }
}

// ---------------- layernorm over rows of 1024 f32 ----------------
template<int MODE>
__global__ __launch_bounds__(256)
void ln_k(const float* __restrict__ Y, const float* __restrict__ w, const float* __restrict__ b,
          float* __restrict__ Hf, bf16* __restrict__ Hb) {
    int row = blockIdx.x, tid = threadIdx.x;
    float4 v = reinterpret_cast<const float4*>(Y + (size_t)row * 1024)[tid];
    float s = v.x + v.y + v.z + v.w;
    float q = v.x * v.x + v.y * v.y + v.z * v.z + v.w * v.w;
#pragma unroll
    for (int o = 1; o < 64; o <<= 1) { s += __shfl_xor(s, o); q += __shfl_xor(q, o); }
    __shared__ float ss[4], sq[4];
    if ((tid & 63) == 0) { ss[tid >> 6] = s; sq[tid >> 6] = q; }
    __syncthreads();
    s = ss[0] + ss[1] + ss[2] + ss[3];
    q = sq[0] + sq[1] + sq[2] + sq[3];
    float u = s * (1.f / 1024.f);
    float var = fmaxf(q * (1.f / 1024.f) - u * u, 0.f);
    float rstd = rsqrtf(var + 1e-12f);
    float4 wv = reinterpret_cast<const float4*>(w)[tid];
    float4 bv = reinterpret_cast<const float4*>(b)[tid];
    float o0 = wv.x * (v.x - u) * rstd + bv.x;
    float o1 = wv.y * (v.y - u) * rstd + bv.y;
    float o2 = wv.z * (v.z - u) * rstd + bv.z;
    float o3 = wv.w * (v.w - u) * rstd + bv.w;
    reinterpret_cast<float4*>(Hf + (size_t)row * 1024)[tid] = make_float4(o0, o1, o2, o3);
    if constexpr (MODE == 0) {
        ushort4 ob;
        ob.x = bfbits(o0); ob.y = bfbits(o1); ob.z = bfbits(o2); ob.w = bfbits(o3);
        reinterpret_cast<ushort4*>(Hb)[row * 256 + tid] = ob;
    }
}

// ---- final LN: y = LN(PA + PB + b3 + resid), write f32 out ----
__global__ __launch_bounds__(256)
void ln2k(const float* __restrict__ PA, const float* __restrict__ PB,
          const float* __restrict__ b3, const float* __restrict__ resid,
          const float* __restrict__ w, const float* __restrict__ b,
          float* __restrict__ out) {
    int row = blockIdx.x, tid = threadIdx.x;
    size_t off = (size_t)row * 256 + tid;
    float4 pa = reinterpret_cast<const float4*>(PA)[off];
    float4 pb = reinterpret_cast<const float4*>(PB)[off];
    float4 bi = reinterpret_cast<const float4*>(b3)[tid];
    float4 rs = reinterpret_cast<const float4*>(resid)[off];
    float4 v = make_float4(pa.x + pb.x + bi.x + rs.x, pa.y + pb.y + bi.y + rs.y,
                           pa.z + pb.z + bi.z + rs.z, pa.w + pb.w + bi.w + rs.w);
    float s = v.x + v.y + v.z + v.w;
    float q = v.x * v.x + v.y * v.y + v.z * v.z + v.w * v.w;
#pragma unroll
    for (int o = 1; o < 64; o <<= 1) { s += __shfl_xor(s, o); q += __shfl_xor(q, o); }
    __shared__ float ss[4], sq[4];
    if ((tid & 63) == 0) { ss[tid >> 6] = s; sq[tid >> 6] = q; }
    __syncthreads();
    s = ss[0] + ss[1] + ss[2] + ss[3];
    q = sq[0] + sq[1] + sq[2] + sq[3];
    float u = s * (1.f / 1024.f);
    float var = fmaxf(q * (1.f / 1024.f) - u * u, 0.f);
    float rstd = rsqrtf(var + 1e-12f);
    float4 wv = reinterpret_cast<const float4*>(w)[tid];
    float4 bv = reinterpret_cast<const float4*>(b)[tid];
    float4 o4;
    o4.x = wv.x * (v.x - u) * rstd + bv.x;
    o4.y = wv.y * (v.y - u) * rstd + bv.y;
    o4.z = wv.z * (v.z - u) * rstd + bv.z;
    o4.w = wv.w * (v.w - u) * rstd + bv.w;
    reinterpret_cast<float4*>(out)[off] = o4;
}

extern "C" void kernel_launch(void* const* d_in, const int* in_sizes, int n_in,
                              void* d_out, int out_size, void* d_ws, size_t ws_size,
                              hipStream_t stream) {
    (void)in_sizes; (void)n_in; (void)out_size; (void)ws_size;
    const float* x    = (const float*)d_in[0];
    const float* Wq   = (const float*)d_in[2];
    const float* bq   = (const float*)d_in[3];
    const float* Wk   = (const float*)d_in[4];
    const float* bk   = (const float*)d_in[5];
    const float* Wv   = (const float*)d_in[6];
    const float* bv   = (const float*)d_in[7];
    const float* Wo   = (const float*)d_in[8];
    const float* bo   = (const float*)d_in[9];
    const float* ln1w = (const float*)d_in[10];
    const float* ln1b = (const float*)d_in[11];
    const float* W1   = (const float*)d_in[12];
    const float* b1   = (const float*)d_in[13];
    const float* W2   = (const float*)d_in[14];
    const float* b2   = (const float*)d_in[15];
    const float* W3   = (const float*)d_in[16];
    const float* b3   = (const float*)d_in[17];
    const float* ln2w = (const float*)d_in[18];
    const float* ln2b = (const float*)d_in[19];

    char* ws = (char*)d_ws;
    bf16*  XB    = (bf16*)(ws + 0);
    bf16*  WQKVB = (bf16*)(ws + 16777216);
    bf16*  WOB   = (bf16*)(ws + 23068672);
    bf16*  W1B   = (bf16*)(ws + 25165824);
    bf16*  W2B   = (bf16*)(ws + 29360128);
    bf16*  W3B   = (bf16*)(ws + 46137344);
    bf16*  Qb    = (bf16*)(ws + 54525952);
    bf16*  Kb    = (bf16*)(ws + 71303168);
    bf16*  VTb   = (bf16*)(ws + 88080384);    // [B,H,DK,S] (written transposed by QKV epi)
    bf16*  CTX   = (bf16*)(ws + 138412032);
    float* Y2    = (float*)(ws + 155189248);
    float* H32   = (float*)(ws + 188743680);
    bf16*  HB    = (bf16*)(ws + 222298112);
    bf16*  F1    = (bf16*)(ws + 155189248);   // overlays Y2 (dead after LN1)
    bf16*  F2    = (bf16*)(ws + 54525952);    // overlays Qb..VTb (dead after attn)
    float* PW3   = (float*)(ws + 121634816);  // 67 MB span; clobbers CTX/Y2 (dead by W3)

    CastArgs ca;
    ca.src[0] = x;  ca.src[1] = Wq; ca.src[2] = Wk; ca.src[3] = Wv;
    ca.src[4] = Wo; ca.src[5] = W1; ca.src[6] = W2; ca.src[7] = W3;
    ca.end[0] = 2097152; ca.end[1] = 2359296; ca.end[2] = 2621440; ca.end[3] = 2883584;
    ca.end[4] = 3145728; ca.end[5] = 3670016; ca.end[6] = 5767168; ca.end[7] = 6815744;
    castall<<<2048, 256, 0, stream>>>(ca, (ushort4*)ws);

    // QKV: [8192,1024] @ [3072,1024]^T -> Q,K [B,H,S,DK], V -> VT [B,H,DK,S]
    gemm256<0, 0><<<384, 512, 0, stream>>>(XB, WQKVB, 3072, 1024, 1024,
                                           bq, bk, bv, nullptr, Qb, Kb, VTb);
    attn_fused<<<512, 256, 0, stream>>>(Qb, Kb, VTb, CTX);
    // attn_out + x -> Y2 (f32)
    gemm_bt<2><<<512, 256, 0, stream>>>(CTX, WOB, 8192, 1024, 1024, bo, x, (void*)Y2);
    ln_k<0><<<8192, 256, 0, stream>>>(Y2, ln1w, ln1b, H32, HB);
    // MLP
    gemm256<1, 0><<<256, 512, 0, stream>>>(HB, W1B, 2048, 1024, 1024,
                                           b1, nullptr, nullptr, (void*)F1, nullptr, nullptr, nullptr);
    gemm256<1, 0><<<512, 512, 0, stream>>>(F1, W2B, 4096, 2048, 2048,
                                           b2, nullptr, nullptr, (void*)F2, nullptr, nullptr, nullptr);
    // W3 split-K=2 -> f32 partials; reduce+bias+resid+LN fused in ln2k
    gemm256<2, 1><<<256, 512, 0, stream>>>(F2, W3B, 1024, 4096, 2048,
                                           nullptr, nullptr, nullptr, (void*)PW3, nullptr, nullptr, nullptr);
    ln2k<<<8192, 256, 0, stream>>>(PW3, PW3 + 8388608, b3, H32, ln2w, ln2b, (float*)d_out);
}

// Round 12
// 440.323 us; speedup vs baseline: 1.0570x; 1.0058x over previous
//
#include <hip/hip_runtime.h>
#include <hip/hip_bf16.h>

using bf16 = __hip_bfloat16;
typedef __attribute__((ext_vector_type(4))) float f32x4;
typedef __attribute__((ext_vector_type(8))) short bf16x8;

__device__ __forceinline__ unsigned short bfbits(float f) {
    bf16 h = __float2bfloat16(f);
    return __builtin_bit_cast(unsigned short, h);
}

__device__ __forceinline__ void g2l16(const void* g, void* l) {
    __builtin_amdgcn_global_load_lds(
        (const __attribute__((address_space(1))) unsigned int*)g,
        (__attribute__((address_space(3))) unsigned int*)l, 16, 0, 0);
}

// ---------------- fused cast f32 -> bf16 for all 8 tensors (1 launch) ----------------
struct CastArgs {
    const float* src[8];
    int end[8];   // prefix ends in float4 units; end[7] = 6815744
};
__global__ __launch_bounds__(256)
void castall(CastArgs a, ushort4* __restrict__ out) {
    int stride = gridDim.x * blockDim.x;
    for (int i = blockIdx.x * blockDim.x + threadIdx.x; i < 6815744; i += stride) {
        const float* sp; int beg;
        if      (i < a.end[0]) { sp = a.src[0]; beg = 0; }
        else if (i < a.end[1]) { sp = a.src[1]; beg = a.end[0]; }
        else if (i < a.end[2]) { sp = a.src[2]; beg = a.end[1]; }
        else if (i < a.end[3]) { sp = a.src[3]; beg = a.end[2]; }
        else if (i < a.end[4]) { sp = a.src[4]; beg = a.end[3]; }
        else if (i < a.end[5]) { sp = a.src[5]; beg = a.end[4]; }
        else if (i < a.end[6]) { sp = a.src[6]; beg = a.end[5]; }
        else                   { sp = a.src[7]; beg = a.end[6]; }
        float4 v = reinterpret_cast<const float4*>(sp)[i - beg];
        ushort4 o;
        o.x = bfbits(v.x); o.y = bfbits(v.y); o.z = bfbits(v.z); o.w = bfbits(v.w);
        out[i] = o;
    }
}

// ======= 256x256-tile 8-wave GEMM (R4-exact, best measured): ring-3, 1 barrier + vmcnt(4)/K-tile =======
// C = A @ B^T. A:[M,ldk] bf16 rm; Bm:[N,ldk] bf16 rm. BK=32, 96KB LDS ring of 3.
// EPI 0: QKV scatter (+per-tensor bias); Q,K -> [B,H,S,DK], V -> TRANSPOSED [B,H,DK,S]
// EPI 1: relu(acc+bias) -> bf16 [M,N]
// EPI 2: raw f32 acc -> outp + slice*M*N  (split-K partials)
template<int EPI, int SPLITK>
__global__ __launch_bounds__(512, 2)
void gemm256(const bf16* __restrict__ A, const bf16* __restrict__ Bm,
             int N, int ldk, int kloop,
             const float* __restrict__ bias0, const float* __restrict__ bias1,
             const float* __restrict__ bias2,
             void* __restrict__ outp,
             bf16* __restrict__ q_o, bf16* __restrict__ k_o, bf16* __restrict__ v_o) {
    __shared__ __align__(16) char lds[98304];
    const int tid = threadIdx.x;
    const int lane = tid & 63, wave = tid >> 6;
    const int rlo = lane & 15, g = lane >> 4;
    const int wr = wave >> 2, wc = wave & 3;
    const int nbn = N >> 8;
    const int nwg = gridDim.x;
    int wg = (int)blockIdx.x;
    wg = (wg & 7) * (nwg >> 3) + (wg >> 3);   // XCD swizzle (nwg % 8 == 0)
    int slice = 0;
    if constexpr (SPLITK) {
        int half = nwg >> 1;
        slice = (wg >= half) ? 1 : 0;
        wg -= slice * half;
    }
    const int bm = wg / nbn, bn = wg % nbn;
    const size_t ldb = (size_t)ldk * 2;
    const char* abase = (const char*)A + ((size_t)bm << 8) * ldb + (size_t)slice * kloop * 2;
    const char* bbase = (const char*)Bm + ((size_t)bn << 8) * ldb + (size_t)slice * kloop * 2;

    const int P = tid * 16;
    const int R = P >> 7;
    const int qs = (P & 127) ^ ((R & 7) << 4);          // unswizzle
    const size_t goff0 = (size_t)(R * 2 + (qs >> 6)) * ldb + (qs & 63);
    const size_t ghalf = (size_t)128 * ldb;

    const int o_in = (((rlo & 1) << 6) | (g << 4)) ^ (((rlo >> 1) & 7) << 4);
    const int aoff = wr * 8192 + (rlo >> 1) * 128 + o_in;
    const int boff = 16384 + (wc >> 1) * 8192 + (wc & 1) * 4096 + (rlo >> 1) * 128 + o_in;

    const f32x4 fz = {0.f, 0.f, 0.f, 0.f};
    f32x4 acc[8][4];
#pragma unroll
    for (int i = 0; i < 8; ++i)
#pragma unroll
        for (int j = 0; j < 4; ++j) acc[i][j] = fz;

    auto stA = [&](int buf, int h, int kt) {
        g2l16(abase + goff0 + (size_t)h * ghalf + (size_t)kt * 64,
              lds + buf * 32768 + h * 8192 + P);
    };
    auto stB = [&](int buf, int h, int kt) {
        g2l16(bbase + goff0 + (size_t)h * ghalf + (size_t)kt * 64,
              lds + buf * 32768 + 16384 + h * 8192 + P);
    };

    // prologue: tiles 0,1 staged; wait tile0 (tile1's 4 stay in flight)
    stA(0, 0, 0); stA(0, 1, 0); stB(0, 0, 0); stB(0, 1, 0);
    stA(1, 0, 1); stA(1, 1, 1); stB(1, 0, 1); stB(1, 1, 1);
    asm volatile("s_waitcnt vmcnt(4)" ::: "memory");
    __builtin_amdgcn_s_barrier();
    __builtin_amdgcn_sched_barrier(0);

    const int NT = kloop >> 5;
    for (int kt = 0; kt < NT; ++kt) {
        const char* lb = lds + (kt % 3) * 32768;
        const int nbuf = (kt + 2) % 3;
        const bool pre = (kt + 2) < NT;

        bf16x8 bfr[4], afr[4];
#pragma unroll
        for (int nf = 0; nf < 4; ++nf)
            bfr[nf] = *reinterpret_cast<const bf16x8*>(lb + nf * 1024 + boff);
#pragma unroll
        for (int i = 0; i < 4; ++i)
            afr[i] = *reinterpret_cast<const bf16x8*>(lb + i * 1024 + aoff);
        if (pre) { stA(nbuf, 0, kt + 2); stA(nbuf, 1, kt + 2); }
        asm volatile("s_waitcnt lgkmcnt(0)");
        __builtin_amdgcn_s_setprio(1);
#pragma unroll
        for (int i = 0; i < 4; ++i)
#pragma unroll
            for (int nf = 0; nf < 4; ++nf)
                acc[i][nf] = __builtin_amdgcn_mfma_f32_16x16x32_bf16(afr[i], bfr[nf], acc[i][nf], 0, 0, 0);
        __builtin_amdgcn_s_setprio(0);

#pragma unroll
        for (int i = 0; i < 4; ++i)
            afr[i] = *reinterpret_cast<const bf16x8*>(lb + (4 + i) * 1024 + aoff);
        if (pre) { stB(nbuf, 0, kt + 2); stB(nbuf, 1, kt + 2); }
        asm volatile("s_waitcnt lgkmcnt(0)");
        __builtin_amdgcn_s_setprio(1);
#pragma unroll
        for (int i = 0; i < 4; ++i)
#pragma unroll
            for (int nf = 0; nf < 4; ++nf)
                acc[4 + i][nf] = __builtin_amdgcn_mfma_f32_16x16x32_bf16(afr[i], bfr[nf], acc[4 + i][nf], 0, 0, 0);
        __builtin_amdgcn_s_setprio(0);

        if (pre) {
            asm volatile("s_waitcnt vmcnt(4)" ::: "memory");   // tile kt+1 landed
        } else if (kt + 1 < NT) {
            asm volatile("s_waitcnt vmcnt(0)" ::: "memory");
        }
        if (kt + 1 < NT) {
            __builtin_amdgcn_s_barrier();
            __builtin_amdgcn_sched_barrier(0);
        }
    }

    const int gm0 = (bm << 8) + wr * 128;
    const int gn0 = (bn << 8) + wc * 64;
#pragma unroll
    for (int mf = 0; mf < 8; ++mf) {
#pragma unroll
        for (int nf = 0; nf < 4; ++nf) {
            const int gnc = gn0 + nf * 16 + rlo;
#pragma unroll
            for (int r = 0; r < 4; ++r) {
                const int gmr = gm0 + mf * 16 + g * 4 + r;
                float val = acc[mf][nf][r];
                if constexpr (EPI == 0) {
                    int t = gnc >> 10;
                    const float* bp = (t == 0) ? bias0 : ((t == 1) ? bias1 : bias2);
                    val += bp[gnc & 1023];
                    bf16* dst = (t == 0) ? q_o : ((t == 1) ? k_o : v_o);
                    int hh = (gnc >> 7) & 7, d = gnc & 127;
                    int bb = gmr >> 7, s = gmr & 127;
                    size_t idx = (t == 2)
                        ? ((((size_t)bb * 8 + hh) * 128 + d) * 128 + s)   // V stored transposed
                        : ((((size_t)bb * 8 + hh) * 128 + s) * 128 + d);
                    dst[idx] = __float2bfloat16(val);
                } else if constexpr (EPI == 1) {
                    val = fmaxf(val + bias0[gnc], 0.f);
                    ((bf16*)outp)[(size_t)gmr * N + gnc] = __float2bfloat16(val);
                } else {
                    float* pp = (float*)outp + (size_t)slice * 8388608;
                    pp[(size_t)gmr * N + gnc] = val;
                }
            }
        }
    }
}

// ---------------- GEMM: C = A @ B^T, 128^2 tile (kept for Wo, N=1024) ----------------
template<int EPI>
__global__ __launch_bounds__(256, 2)
void gemm_bt(const bf16* __restrict__ A, const bf16* __restrict__ Bm,
             int M, int N, int K,
             const float* __restrict__ bias0, const float* __restrict__ resid,
             void* __restrict__ outp) {
    (void)M;
    __shared__ __align__(16) char As[8192];
    __shared__ __align__(16) char Bs[8192];
    int tid = threadIdx.x, wave = tid >> 6, lane = tid & 63;
    int nbn = N >> 7;
    int bm = blockIdx.x / nbn, bn = blockIdx.x % nbn;
    int wm = (wave >> 1) << 6, wn = (wave & 1) << 6;
    int rlo = lane & 15, g = lane >> 4;

    const char* abase = (const char*)(A + (size_t)(bm << 7) * K);
    const char* bbase = (const char*)(Bm + (size_t)(bn << 7) * K);

    const f32x4 fzero = {0.f, 0.f, 0.f, 0.f};
    f32x4 acc[4][4];
#pragma unroll
    for (int i = 0; i < 4; ++i)
#pragma unroll
        for (int j = 0; j < 4; ++j) acc[i][j] = fzero;

    int L0 = wave * 2048 + lane * 16;
    size_t ldbyte = (size_t)K * 2;

    for (int k0 = 0; k0 < K; k0 += 32) {
#pragma unroll
        for (int j = 0; j < 2; ++j) {
            int L = L0 + j * 1024;
            int row = L >> 6;
            int cb = (L & 63) ^ (((row >> 1) & 3) << 4);
            g2l16(abase + (size_t)row * ldbyte + (size_t)k0 * 2 + cb, As + wave * 2048 + j * 1024);
            g2l16(bbase + (size_t)row * ldbyte + (size_t)k0 * 2 + cb, Bs + wave * 2048 + j * 1024);
        }
        __syncthreads();
        bf16x8 af[4], bf8[4];
#pragma unroll
        for (int i = 0; i < 4; ++i) {
            int ra = wm + i * 16 + rlo;
            af[i] = *reinterpret_cast<const bf16x8*>(As + ra * 64 + ((g * 16) ^ (((ra >> 1) & 3) << 4)));
            int rb = wn + i * 16 + rlo;
            bf8[i] = *reinterpret_cast<const bf16x8*>(Bs + rb * 64 + ((g * 16) ^ (((rb >> 1) & 3) << 4)));
        }
#pragma unroll
        for (int mi = 0; mi < 4; ++mi)
#pragma unroll
            for (int ni = 0; ni < 4; ++ni)
                acc[mi][ni] = __builtin_amdgcn_mfma_f32_16x16x32_bf16(af[mi], bf8[ni], acc[mi][ni], 0, 0, 0);
        __syncthreads();
    }

    int gm0 = (bm << 7) + wm, gn0 = (bn << 7) + wn;
#pragma unroll
    for (int mi = 0; mi < 4; ++mi) {
#pragma unroll
        for (int ni = 0; ni < 4; ++ni) {
            int gnc = gn0 + ni * 16 + rlo;
#pragma unroll
            for (int r = 0; r < 4; ++r) {
                int gmr = gm0 + mi * 16 + g * 4 + r;
                float val = acc[mi][ni][r];
                val += bias0[gnc] + resid[(size_t)gmr * N + gnc];
                ((float*)outp)[(size_t)gmr * N + gnc] = val;
            }
        }
    }
}

// ---------------- fused attention per (b,h), 8 waves: CTX = (softmax(QK^T/s) @ V) @ V ----------------
// 512 threads; each wave owns 16 Q-rows -> 2 waves/SIMD (TLP hides softmax VALU under MFMA).
// Q,K: [B,H,S,DK]; VT: [B,H,DK,S]. Qs: Q then P; Ks: K then T; Vs: VT. Swizzle byte ^ ((row&7)<<4).
__global__ __launch_bounds__(512, 1)
void attn_fused(const bf16* __restrict__ Q, const bf16* __restrict__ K,
                const bf16* __restrict__ VT, bf16* __restrict__ CTX) {
    __shared__ __align__(16) char Qs[32768];
    __shared__ __align__(16) char Ks[32768];
    __shared__ __align__(16) char Vs[32768];
    int bh = blockIdx.x, b = bh >> 3, h = bh & 7;
    int tid = threadIdx.x, wave = tid >> 6, lane = tid & 63;
    const char* qsrc = (const char*)(Q + (size_t)bh * 16384);
    const char* ksrc = (const char*)(K + (size_t)bh * 16384);
    const char* vsrc = (const char*)(VT + (size_t)bh * 16384);
#pragma unroll
    for (int j = 0; j < 4; ++j) {
        int L = j * 8192 + tid * 16;
        int row = L >> 8;
        int cb = (L & 255) ^ ((row & 7) << 4);
        g2l16(qsrc + row * 256 + cb, Qs + j * 8192 + tid * 16);
        g2l16(ksrc + row * 256 + cb, Ks + j * 8192 + tid * 16);
        g2l16(vsrc + row * 256 + cb, Vs + j * 8192 + tid * 16);
    }
    __syncthreads();
    int rlo = lane & 15, g = lane >> 4;
    const f32x4 fzero = {0.f, 0.f, 0.f, 0.f};
    const int mrow = wave * 16;   // this wave's 16 Q-rows

    // ---- QK^T ----
    f32x4 acc[8];
#pragma unroll
    for (int ni = 0; ni < 8; ++ni) acc[ni] = fzero;
#pragma unroll
    for (int kk = 0; kk < 4; ++kk) {
        bf16x8 aq, bk8[8];
        {
            int row = mrow + rlo;
            aq = *reinterpret_cast<const bf16x8*>(Qs + row * 256 + ((kk * 64 + g * 16) ^ ((row & 7) << 4)));
        }
#pragma unroll
        for (int ni = 0; ni < 8; ++ni) {
            int row = ni * 16 + rlo;
            bk8[ni] = *reinterpret_cast<const bf16x8*>(Ks + row * 256 + ((kk * 64 + g * 16) ^ ((row & 7) << 4)));
        }
#pragma unroll
        for (int ni = 0; ni < 8; ++ni)
            acc[ni] = __builtin_amdgcn_mfma_f32_16x16x32_bf16(aq, bk8[ni], acc[ni], 0, 0, 0);
    }

    // ---- softmax -> P into Qs (rows wave-private) ----
    const float scale = 0.088388347648318447f;  // 1/sqrt(128)
#pragma unroll
    for (int r = 0; r < 4; ++r) {
        float m = -3e38f;
#pragma unroll
        for (int ni = 0; ni < 8; ++ni) m = fmaxf(m, acc[ni][r]);
#pragma unroll
        for (int o = 1; o < 16; o <<= 1) m = fmaxf(m, __shfl_xor(m, o));
        m *= scale;
        float e[8];
        float sum = 0.f;
#pragma unroll
        for (int ni = 0; ni < 8; ++ni) { e[ni] = __expf(acc[ni][r] * scale - m); sum += e[ni]; }
#pragma unroll
        for (int o = 1; o < 16; o <<= 1) sum += __shfl_xor(sum, o);
        float inv = 1.f / sum;
        int qrow = mrow + g * 4 + r;
#pragma unroll
        for (int ni = 0; ni < 8; ++ni) {
            int cbyte = ((ni * 16 + rlo) * 2) ^ ((qrow & 7) << 4);
            *(unsigned short*)(Qs + qrow * 256 + cbyte) = bfbits(e[ni] * inv);
        }
    }
    __syncthreads();   // all K reads done; P visible

    // ---- PV: A = P (Qs), B = VT (Vs) ----
    f32x4 accT[8];
#pragma unroll
    for (int ni = 0; ni < 8; ++ni) accT[ni] = fzero;
#pragma unroll
    for (int kk = 0; kk < 4; ++kk) {
        bf16x8 ap, bv8[8];
        {
            int row = mrow + rlo;
            ap = *reinterpret_cast<const bf16x8*>(Qs + row * 256 + ((kk * 64 + g * 16) ^ ((row & 7) << 4)));
        }
#pragma unroll
        for (int ni = 0; ni < 8; ++ni) {
            int row = ni * 16 + rlo;
            bv8[ni] = *reinterpret_cast<const bf16x8*>(Vs + row * 256 + ((kk * 64 + g * 16) ^ ((row & 7) << 4)));
        }
#pragma unroll
        for (int ni = 0; ni < 8; ++ni)
            accT[ni] = __builtin_amdgcn_mfma_f32_16x16x32_bf16(ap, bv8[ni], accT[ni], 0, 0, 0);
    }
    // ---- T -> Ks (rows wave-private) ----
#pragma unroll
    for (int ni = 0; ni < 8; ++ni)
#pragma unroll
        for (int r = 0; r < 4; ++r) {
            int trow = mrow + g * 4 + r;
            int cbyte = ((ni * 16 + rlo) * 2) ^ ((trow & 7) << 4);
            *(unsigned short*)(Ks + trow * 256 + cbyte) = bfbits(accT[ni][r]);
        }
    __syncthreads();

    // ---- C2 = T @ VT^T ----
    f32x4 accC[8];
#pragma unroll
    for (int ni = 0; ni < 8; ++ni) accC[ni] = fzero;
#pragma unroll
    for (int kk = 0; kk < 4; ++kk) {
        bf16x8 at, bv8[8];
        {
            int row = mrow + rlo;
            at = *reinterpret_cast<const bf16x8*>(Ks + row * 256 + ((kk * 64 + g * 16) ^ ((row & 7) << 4)));
        }
#pragma unroll
        for (int ni = 0; ni < 8; ++ni) {
            int row = ni * 16 + rlo;
            bv8[ni] = *reinterpret_cast<const bf16x8*>(Vs + row * 256 + ((kk * 64 + g * 16) ^ ((row & 7) << 4)));
        }
#pragma unroll
        for (int ni = 0; ni < 8; ++ni)
            accC[ni] = __builtin_amdgcn_mfma_f32_16x16x32_bf16(at, bv8[ni], accC[ni], 0, 0, 0);
    }
    unsigned short* cdst = (unsigned short*)CTX;
#pragma unroll
    for (int ni = 0; ni < 8; ++ni)
#pragma unroll
        for (int r = 0; r < 4; ++r) {
            int q = mrow + g * 4 + r;
            int gm = b * 128 + q;
            int col = h * 128 + ni * 16 + rlo;
            cdst[(size_t)gm * 1024 + col] = bfbits(accC[ni][r]);
        }
}

// ---------------- layernorm over rows of 1024 f32 ----------------
template<int MODE>
__global__ __launch_bounds__(256)
void ln_k(const float* __restrict__ Y, const float* __restrict__ w, const float* __restrict__ b,
          float* __restrict__ Hf, bf16* __restrict__ Hb) {
    int row = blockIdx.x, tid = threadIdx.x;
    float4 v = reinterpret_cast<const float4*>(Y + (size_t)row * 1024)[tid];
    float s = v.x + v.y + v.z + v.w;
    float q = v.x * v.x + v.y * v.y + v.z * v.z + v.w * v.w;
#pragma unroll
    for (int o = 1; o < 64; o <<= 1) { s += __shfl_xor(s, o); q += __shfl_xor(q, o); }
    __shared__ float ss[4], sq[4];
    if ((tid & 63) == 0) { ss[tid >> 6] = s; sq[tid >> 6] = q; }
    __syncthreads();
    s = ss[0] + ss[1] + ss[2] + ss[3];
    q = sq[0] + sq[1] + sq[2] + sq[3];
    float u = s * (1.f / 1024.f);
    float var = fmaxf(q * (1.f / 1024.f) - u * u, 0.f);
    float rstd = rsqrtf(var + 1e-12f);
    float4 wv = reinterpret_cast<const float4*>(w)[tid];
    float4 bv = reinterpret_cast<const float4*>(b)[tid];
    float o0 = wv.x * (v.x - u) * rstd + bv.x;
    float o1 = wv.y * (v.y - u) * rstd + bv.y;
    float o2 = wv.z * (v.z - u) * rstd + bv.z;
    float o3 = wv.w * (v.w - u) * rstd + bv.w;
    reinterpret_cast<float4*>(Hf + (size_t)row * 1024)[tid] = make_float4(o0, o1, o2, o3);
    if constexpr (MODE == 0) {
        ushort4 ob;
        ob.x = bfbits(o0); ob.y = bfbits(o1); ob.z = bfbits(o2); ob.w = bfbits(o3);
        reinterpret_cast<ushort4*>(Hb)[row * 256 + tid] = ob;
    }
}

// ---- final LN: y = LN(PA + PB + b3 + resid), write f32 out ----
__global__ __launch_bounds__(256)
void ln2k(const float* __restrict__ PA, const float* __restrict__ PB,
          const float* __restrict__ b3, const float* __restrict__ resid,
          const float* __restrict__ w, const float* __restrict__ b,
          float* __restrict__ out) {
    int row = blockIdx.x, tid = threadIdx.x;
    size_t off = (size_t)row * 256 + tid;
    float4 pa = reinterpret_cast<const float4*>(PA)[off];
    float4 pb = reinterpret_cast<const float4*>(PB)[off];
    float4 bi = reinterpret_cast<const float4*>(b3)[tid];
    float4 rs = reinterpret_cast<const float4*>(resid)[off];
    float4 v = make_float4(pa.x + pb.x + bi.x + rs.x, pa.y + pb.y + bi.y + rs.y,
                           pa.z + pb.z + bi.z + rs.z, pa.w + pb.w + bi.w + rs.w);
    float s = v.x + v.y + v.z + v.w;
    float q = v.x * v.x + v.y * v.y + v.z * v.z + v.w * v.w;
#pragma unroll
    for (int o = 1; o < 64; o <<= 1) { s += __shfl_xor(s, o); q += __shfl_xor(q, o); }
    __shared__ float ss[4], sq[4];
    if ((tid & 63) == 0) { ss[tid >> 6] = s; sq[tid >> 6] = q; }
    __syncthreads();
    s = ss[0] + ss[1] + ss[2] + ss[3];
    q = sq[0] + sq[1] + sq[2] + sq[3];
    float u = s * (1.f / 1024.f);
    float var = fmaxf(q * (1.f / 1024.f) - u * u, 0.f);
    float rstd = rsqrtf(var + 1e-12f);
    float4 wv = reinterpret_cast<const float4*>(w)[tid];
    float4 bv = reinterpret_cast<const float4*>(b)[tid];
    float4 o4;
    o4.x = wv.x * (v.x - u) * rstd + bv.x;
    o4.y = wv.y * (v.y - u) * rstd + bv.y;
    o4.z = wv.z * (v.z - u) * rstd + bv.z;
    o4.w = wv.w * (v.w - u) * rstd + bv.w;
    reinterpret_cast<float4*>(out)[off] = o4;
}

extern "C" void kernel_launch(void* const* d_in, const int* in_sizes, int n_in,
                              void* d_out, int out_size, void* d_ws, size_t ws_size,
                              hipStream_t stream) {
    (void)in_sizes; (void)n_in; (void)out_size; (void)ws_size;
    const float* x    = (const float*)d_in[0];
    const float* Wq   = (const float*)d_in[2];
    const float* bq   = (const float*)d_in[3];
    const float* Wk   = (const float*)d_in[4];
    const float* bk   = (const float*)d_in[5];
    const float* Wv   = (const float*)d_in[6];
    const float* bv   = (const float*)d_in[7];
    const float* Wo   = (const float*)d_in[8];
    const float* bo   = (const float*)d_in[9];
    const float* ln1w = (const float*)d_in[10];
    const float* ln1b = (const float*)d_in[11];
    const float* W1   = (const float*)d_in[12];
    const float* b1   = (const float*)d_in[13];
    const float* W2   = (const float*)d_in[14];
    const float* b2   = (const float*)d_in[15];
    const float* W3   = (const float*)d_in[16];
    const float* b3   = (const float*)d_in[17];
    const float* ln2w = (const float*)d_in[18];
    const float* ln2b = (const float*)d_in[19];

    char* ws = (char*)d_ws;
    bf16*  XB    = (bf16*)(ws + 0);
    bf16*  WQKVB = (bf16*)(ws + 16777216);
    bf16*  WOB   = (bf16*)(ws + 23068672);
    bf16*  W1B   = (bf16*)(ws + 25165824);
    bf16*  W2B   = (bf16*)(ws + 29360128);
    bf16*  W3B   = (bf16*)(ws + 46137344);
    bf16*  Qb    = (bf16*)(ws + 54525952);
    bf16*  Kb    = (bf16*)(ws + 71303168);
    bf16*  VTb   = (bf16*)(ws + 88080384);    // [B,H,DK,S] (written transposed by QKV epi)
    bf16*  CTX   = (bf16*)(ws + 138412032);
    float* Y2    = (float*)(ws + 155189248);
    float* H32   = (float*)(ws + 188743680);
    bf16*  HB    = (bf16*)(ws + 222298112);
    bf16*  F1    = (bf16*)(ws + 155189248);   // overlays Y2 (dead after LN1)
    bf16*  F2    = (bf16*)(ws + 54525952);    // overlays Qb..VTb (dead after attn)
    float* PW3   = (float*)(ws + 121634816);  // 67 MB span; clobbers CTX/Y2 (dead by W3)

    CastArgs ca;
    ca.src[0] = x;  ca.src[1] = Wq; ca.src[2] = Wk; ca.src[3] = Wv;
    ca.src[4] = Wo; ca.src[5] = W1; ca.src[6] = W2; ca.src[7] = W3;
    ca.end[0] = 2097152; ca.end[1] = 2359296; ca.end[2] = 2621440; ca.end[3] = 2883584;
    ca.end[4] = 3145728; ca.end[5] = 3670016; ca.end[6] = 5767168; ca.end[7] = 6815744;
    castall<<<2048, 256, 0, stream>>>(ca, (ushort4*)ws);

    // QKV: [8192,1024] @ [3072,1024]^T -> Q,K [B,H,S,DK], V -> VT [B,H,DK,S]
    gemm256<0, 0><<<384, 512, 0, stream>>>(XB, WQKVB, 3072, 1024, 1024,
                                           bq, bk, bv, nullptr, Qb, Kb, VTb);
    attn_fused<<<512, 512, 0, stream>>>(Qb, Kb, VTb, CTX);
    // attn_out + x -> Y2 (f32)
    gemm_bt<2><<<512, 256, 0, stream>>>(CTX, WOB, 8192, 1024, 1024, bo, x, (void*)Y2);
    ln_k<0><<<8192, 256, 0, stream>>>(Y2, ln1w, ln1b, H32, HB);
    // MLP
    gemm256<1, 0><<<256, 512, 0, stream>>>(HB, W1B, 2048, 1024, 1024,
                                           b1, nullptr, nullptr, (void*)F1, nullptr, nullptr, nullptr);
    gemm256<1, 0><<<512, 512, 0, stream>>>(F1, W2B, 4096, 2048, 2048,
                                           b2, nullptr, nullptr, (void*)F2, nullptr, nullptr, nullptr);
    // W3 split-K=2 -> f32 partials; reduce+bias+resid+LN fused in ln2k
    gemm256<2, 1><<<256, 512, 0, stream>>>(F2, W3B, 1024, 4096, 2048,
                                           nullptr, nullptr, nullptr, (void*)PW3, nullptr, nullptr, nullptr);
    ln2k<<<8192, 256, 0, stream>>>(PW3, PW3 + 8388608, b3, H32, ln2w, ln2b, (float*)d_out);
}

// Round 13
// 424.093 us; speedup vs baseline: 1.0975x; 1.0383x over previous
//
#include <hip/hip_runtime.h>
#include <hip/hip_bf16.h>

using bf16 = __hip_bfloat16;
typedef __attribute__((ext_vector_type(4))) float f32x4;
typedef __attribute__((ext_vector_type(8))) short bf16x8;

__device__ __forceinline__ unsigned short bfbits(float f) {
    bf16 h = __float2bfloat16(f);
    return __builtin_bit_cast(unsigned short, h);
}
__device__ __forceinline__ float b2f(unsigned short u) {
    unsigned int x = ((unsigned int)u) << 16;
    return __builtin_bit_cast(float, x);
}

__device__ __forceinline__ void g2l16(const void* g, void* l) {
    __builtin_amdgcn_global_load_lds(
        (const __attribute__((address_space(1))) unsigned int*)g,
        (__attribute__((address_space(3))) unsigned int*)l, 16, 0, 0);
}

// ---------------- fused cast f32 -> bf16 for all 8 tensors (1 launch) ----------------
struct CastArgs {
    const float* src[8];
    int end[8];   // prefix ends in float4 units; end[7] = 6815744
};
__global__ __launch_bounds__(256)
void castall(CastArgs a, ushort4* __restrict__ out) {
    int stride = gridDim.x * blockDim.x;
    for (int i = blockIdx.x * blockDim.x + threadIdx.x; i < 6815744; i += stride) {
        const float* sp; int beg;
        if      (i < a.end[0]) { sp = a.src[0]; beg = 0; }
        else if (i < a.end[1]) { sp = a.src[1]; beg = a.end[0]; }
        else if (i < a.end[2]) { sp = a.src[2]; beg = a.end[1]; }
        else if (i < a.end[3]) { sp = a.src[3]; beg = a.end[2]; }
        else if (i < a.end[4]) { sp = a.src[4]; beg = a.end[3]; }
        else if (i < a.end[5]) { sp = a.src[5]; beg = a.end[4]; }
        else if (i < a.end[6]) { sp = a.src[6]; beg = a.end[5]; }
        else                   { sp = a.src[7]; beg = a.end[6]; }
        float4 v = reinterpret_cast<const float4*>(sp)[i - beg];
        ushort4 o;
        o.x = bfbits(v.x); o.y = bfbits(v.y); o.z = bfbits(v.z); o.w = bfbits(v.w);
        out[i] = o;
    }
}

// ======= 256x256-tile 8-wave GEMM (R4-exact, best measured): ring-3, 1 barrier + vmcnt(4)/K-tile =======
// C = A @ B^T. A:[M,ldk] bf16 rm; Bm:[N,ldk] bf16 rm. BK=32, 96KB LDS ring of 3.
// EPI 0: QKV scatter (+per-tensor bias); Q,K -> [B,H,S,DK], V -> TRANSPOSED [B,H,DK,S]
// EPI 1: relu(acc+bias) -> bf16 [M,N]
// EPI 2: raw f32 acc -> outp + slice*M*N  (split-K partials)
template<int EPI, int SPLITK>
__global__ __launch_bounds__(512, 2)
void gemm256(const bf16* __restrict__ A, const bf16* __restrict__ Bm,
             int N, int ldk, int kloop,
             const float* __restrict__ bias0, const float* __restrict__ bias1,
             const float* __restrict__ bias2,
             void* __restrict__ outp,
             bf16* __restrict__ q_o, bf16* __restrict__ k_o, bf16* __restrict__ v_o) {
    __shared__ __align__(16) char lds[98304];
    const int tid = threadIdx.x;
    const int lane = tid & 63, wave = tid >> 6;
    const int rlo = lane & 15, g = lane >> 4;
    const int wr = wave >> 2, wc = wave & 3;
    const int nbn = N >> 8;
    const int nwg = gridDim.x;
    int wg = (int)blockIdx.x;
    wg = (wg & 7) * (nwg >> 3) + (wg >> 3);   // XCD swizzle (nwg % 8 == 0)
    int slice = 0;
    if constexpr (SPLITK) {
        int half = nwg >> 1;
        slice = (wg >= half) ? 1 : 0;
        wg -= slice * half;
    }
    const int bm = wg / nbn, bn = wg % nbn;
    const size_t ldb = (size_t)ldk * 2;
    const char* abase = (const char*)A + ((size_t)bm << 8) * ldb + (size_t)slice * kloop * 2;
    const char* bbase = (const char*)Bm + ((size_t)bn << 8) * ldb + (size_t)slice * kloop * 2;

    const int P = tid * 16;
    const int R = P >> 7;
    const int qs = (P & 127) ^ ((R & 7) << 4);          // unswizzle
    const size_t goff0 = (size_t)(R * 2 + (qs >> 6)) * ldb + (qs & 63);
    const size_t ghalf = (size_t)128 * ldb;

    const int o_in = (((rlo & 1) << 6) | (g << 4)) ^ (((rlo >> 1) & 7) << 4);
    const int aoff = wr * 8192 + (rlo >> 1) * 128 + o_in;
    const int boff = 16384 + (wc >> 1) * 8192 + (wc & 1) * 4096 + (rlo >> 1) * 128 + o_in;

    const f32x4 fz = {0.f, 0.f, 0.f, 0.f};
    f32x4 acc[8][4];
#pragma unroll
    for (int i = 0; i < 8; ++i)
#pragma unroll
        for (int j = 0; j < 4; ++j) acc[i][j] = fz;

    auto stA = [&](int buf, int h, int kt) {
        g2l16(abase + goff0 + (size_t)h * ghalf + (size_t)kt * 64,
              lds + buf * 32768 + h * 8192 + P);
    };
    auto stB = [&](int buf, int h, int kt) {
        g2l16(bbase + goff0 + (size_t)h * ghalf + (size_t)kt * 64,
              lds + buf * 32768 + 16384 + h * 8192 + P);
    };

    // prologue: tiles 0,1 staged; wait tile0 (tile1's 4 stay in flight)
    stA(0, 0, 0); stA(0, 1, 0); stB(0, 0, 0); stB(0, 1, 0);
    stA(1, 0, 1); stA(1, 1, 1); stB(1, 0, 1); stB(1, 1, 1);
    asm volatile("s_waitcnt vmcnt(4)" ::: "memory");
    __builtin_amdgcn_s_barrier();
    __builtin_amdgcn_sched_barrier(0);

    const int NT = kloop >> 5;
    for (int kt = 0; kt < NT; ++kt) {
        const char* lb = lds + (kt % 3) * 32768;
        const int nbuf = (kt + 2) % 3;
        const bool pre = (kt + 2) < NT;

        bf16x8 bfr[4], afr[4];
#pragma unroll
        for (int nf = 0; nf < 4; ++nf)
            bfr[nf] = *reinterpret_cast<const bf16x8*>(lb + nf * 1024 + boff);
#pragma unroll
        for (int i = 0; i < 4; ++i)
            afr[i] = *reinterpret_cast<const bf16x8*>(lb + i * 1024 + aoff);
        if (pre) { stA(nbuf, 0, kt + 2); stA(nbuf, 1, kt + 2); }
        asm volatile("s_waitcnt lgkmcnt(0)");
        __builtin_amdgcn_s_setprio(1);
#pragma unroll
        for (int i = 0; i < 4; ++i)
#pragma unroll
            for (int nf = 0; nf < 4; ++nf)
                acc[i][nf] = __builtin_amdgcn_mfma_f32_16x16x32_bf16(afr[i], bfr[nf], acc[i][nf], 0, 0, 0);
        __builtin_amdgcn_s_setprio(0);

#pragma unroll
        for (int i = 0; i < 4; ++i)
            afr[i] = *reinterpret_cast<const bf16x8*>(lb + (4 + i) * 1024 + aoff);
        if (pre) { stB(nbuf, 0, kt + 2); stB(nbuf, 1, kt + 2); }
        asm volatile("s_waitcnt lgkmcnt(0)");
        __builtin_amdgcn_s_setprio(1);
#pragma unroll
        for (int i = 0; i < 4; ++i)
#pragma unroll
            for (int nf = 0; nf < 4; ++nf)
                acc[4 + i][nf] = __builtin_amdgcn_mfma_f32_16x16x32_bf16(afr[i], bfr[nf], acc[4 + i][nf], 0, 0, 0);
        __builtin_amdgcn_s_setprio(0);

        if (pre) {
            asm volatile("s_waitcnt vmcnt(4)" ::: "memory");   // tile kt+1 landed
        } else if (kt + 1 < NT) {
            asm volatile("s_waitcnt vmcnt(0)" ::: "memory");
        }
        if (kt + 1 < NT) {
            __builtin_amdgcn_s_barrier();
            __builtin_amdgcn_sched_barrier(0);
        }
    }

    const int gm0 = (bm << 8) + wr * 128;
    const int gn0 = (bn << 8) + wc * 64;
#pragma unroll
    for (int mf = 0; mf < 8; ++mf) {
#pragma unroll
        for (int nf = 0; nf < 4; ++nf) {
            const int gnc = gn0 + nf * 16 + rlo;
#pragma unroll
            for (int r = 0; r < 4; ++r) {
                const int gmr = gm0 + mf * 16 + g * 4 + r;
                float val = acc[mf][nf][r];
                if constexpr (EPI == 0) {
                    int t = gnc >> 10;
                    const float* bp = (t == 0) ? bias0 : ((t == 1) ? bias1 : bias2);
                    val += bp[gnc & 1023];
                    bf16* dst = (t == 0) ? q_o : ((t == 1) ? k_o : v_o);
                    int hh = (gnc >> 7) & 7, d = gnc & 127;
                    int bb = gmr >> 7, s = gmr & 127;
                    size_t idx = (t == 2)
                        ? ((((size_t)bb * 8 + hh) * 128 + d) * 128 + s)   // V stored transposed
                        : ((((size_t)bb * 8 + hh) * 128 + s) * 128 + d);
                    dst[idx] = __float2bfloat16(val);
                } else if constexpr (EPI == 1) {
                    val = fmaxf(val + bias0[gnc], 0.f);
                    ((bf16*)outp)[(size_t)gmr * N + gnc] = __float2bfloat16(val);
                } else {
                    float* pp = (float*)outp + (size_t)slice * 8388608;
                    pp[(size_t)gmr * N + gnc] = val;
                }
            }
        }
    }
}

// ---------------- GEMM: C = A @ B^T, 128^2 tile (Wo, N=1024) ----------------
// EPI: acc + bias + resid(bf16) -> bf16 out (Y2 path all-bf16)
__global__ __launch_bounds__(256, 2)
void gemm_bt(const bf16* __restrict__ A, const bf16* __restrict__ Bm,
             int M, int N, int K,
             const float* __restrict__ bias0, const bf16* __restrict__ resid,
             bf16* __restrict__ outp) {
    (void)M;
    __shared__ __align__(16) char As[8192];
    __shared__ __align__(16) char Bs[8192];
    int tid = threadIdx.x, wave = tid >> 6, lane = tid & 63;
    int nbn = N >> 7;
    int bm = blockIdx.x / nbn, bn = blockIdx.x % nbn;
    int wm = (wave >> 1) << 6, wn = (wave & 1) << 6;
    int rlo = lane & 15, g = lane >> 4;

    const char* abase = (const char*)(A + (size_t)(bm << 7) * K);
    const char* bbase = (const char*)(Bm + (size_t)(bn << 7) * K);

    const f32x4 fzero = {0.f, 0.f, 0.f, 0.f};
    f32x4 acc[4][4];
#pragma unroll
    for (int i = 0; i < 4; ++i)
#pragma unroll
        for (int j = 0; j < 4; ++j) acc[i][j] = fzero;

    int L0 = wave * 2048 + lane * 16;
    size_t ldbyte = (size_t)K * 2;

    for (int k0 = 0; k0 < K; k0 += 32) {
#pragma unroll
        for (int j = 0; j < 2; ++j) {
            int L = L0 + j * 1024;
            int row = L >> 6;
            int cb = (L & 63) ^ (((row >> 1) & 3) << 4);
            g2l16(abase + (size_t)row * ldbyte + (size_t)k0 * 2 + cb, As + wave * 2048 + j * 1024);
            g2l16(bbase + (size_t)row * ldbyte + (size_t)k0 * 2 + cb, Bs + wave * 2048 + j * 1024);
        }
        __syncthreads();
        bf16x8 af[4], bf8[4];
#pragma unroll
        for (int i = 0; i < 4; ++i) {
            int ra = wm + i * 16 + rlo;
            af[i] = *reinterpret_cast<const bf16x8*>(As + ra * 64 + ((g * 16) ^ (((ra >> 1) & 3) << 4)));
            int rb = wn + i * 16 + rlo;
            bf8[i] = *reinterpret_cast<const bf16x8*>(Bs + rb * 64 + ((g * 16) ^ (((rb >> 1) & 3) << 4)));
        }
#pragma unroll
        for (int mi = 0; mi < 4; ++mi)
#pragma unroll
            for (int ni = 0; ni < 4; ++ni)
                acc[mi][ni] = __builtin_amdgcn_mfma_f32_16x16x32_bf16(af[mi], bf8[ni], acc[mi][ni], 0, 0, 0);
        __syncthreads();
    }

    int gm0 = (bm << 7) + wm, gn0 = (bn << 7) + wn;
#pragma unroll
    for (int mi = 0; mi < 4; ++mi) {
#pragma unroll
        for (int ni = 0; ni < 4; ++ni) {
            int gnc = gn0 + ni * 16 + rlo;
#pragma unroll
            for (int r = 0; r < 4; ++r) {
                int gmr = gm0 + mi * 16 + g * 4 + r;
                size_t idx = (size_t)gmr * N + gnc;
                float val = acc[mi][ni][r] + bias0[gnc] +
                            b2f(__builtin_bit_cast(unsigned short, resid[idx]));
                outp[idx] = __float2bfloat16(val);
            }
        }
    }
}

// ---------------- fused attention per (b,h), 8 waves: CTX = (softmax(QK^T/s) @ V) @ V ----------------
__global__ __launch_bounds__(512, 1)
void attn_fused(const bf16* __restrict__ Q, const bf16* __restrict__ K,
                const bf16* __restrict__ VT, bf16* __restrict__ CTX) {
    __shared__ __align__(16) char Qs[32768];
    __shared__ __align__(16) char Ks[32768];
    __shared__ __align__(16) char Vs[32768];
    int bh = blockIdx.x, b = bh >> 3, h = bh & 7;
    int tid = threadIdx.x, wave = tid >> 6, lane = tid & 63;
    const char* qsrc = (const char*)(Q + (size_t)bh * 16384);
    const char* ksrc = (const char*)(K + (size_t)bh * 16384);
    const char* vsrc = (const char*)(VT + (size_t)bh * 16384);
#pragma unroll
    for (int j = 0; j < 4; ++j) {
        int L = j * 8192 + tid * 16;
        int row = L >> 8;
        int cb = (L & 255) ^ ((row & 7) << 4);
        g2l16(qsrc + row * 256 + cb, Qs + j * 8192 + tid * 16);
        g2l16(ksrc + row * 256 + cb, Ks + j * 8192 + tid * 16);
        g2l16(vsrc + row * 256 + cb, Vs + j * 8192 + tid * 16);
    }
    __syncthreads();
    int rlo = lane & 15, g = lane >> 4;
    const f32x4 fzero = {0.f, 0.f, 0.f, 0.f};
    const int mrow = wave * 16;

    f32x4 acc[8];
#pragma unroll
    for (int ni = 0; ni < 8; ++ni) acc[ni] = fzero;
#pragma unroll
    for (int kk = 0; kk < 4; ++kk) {
        bf16x8 aq, bk8[8];
        {
            int row = mrow + rlo;
            aq = *reinterpret_cast<const bf16x8*>(Qs + row * 256 + ((kk * 64 + g * 16) ^ ((row & 7) << 4)));
        }
#pragma unroll
        for (int ni = 0; ni < 8; ++ni) {
            int row = ni * 16 + rlo;
            bk8[ni] = *reinterpret_cast<const bf16x8*>(Ks + row * 256 + ((kk * 64 + g * 16) ^ ((row & 7) << 4)));
        }
#pragma unroll
        for (int ni = 0; ni < 8; ++ni)
            acc[ni] = __builtin_amdgcn_mfma_f32_16x16x32_bf16(aq, bk8[ni], acc[ni], 0, 0, 0);
    }

    const float scale = 0.088388347648318447f;  // 1/sqrt(128)
#pragma unroll
    for (int r = 0; r < 4; ++r) {
        float m = -3e38f;
#pragma unroll
        for (int ni = 0; ni < 8; ++ni) m = fmaxf(m, acc[ni][r]);
#pragma unroll
        for (int o = 1; o < 16; o <<= 1) m = fmaxf(m, __shfl_xor(m, o));
        m *= scale;
        float e[8];
        float sum = 0.f;
#pragma unroll
        for (int ni = 0; ni < 8; ++ni) { e[ni] = __expf(acc[ni][r] * scale - m); sum += e[ni]; }
#pragma unroll
        for (int o = 1; o < 16; o <<= 1) sum += __shfl_xor(sum, o);
        float inv = 1.f / sum;
        int qrow = mrow + g * 4 + r;
#pragma unroll
        for (int ni = 0; ni < 8; ++ni) {
            int cbyte = ((ni * 16 + rlo) * 2) ^ ((qrow & 7) << 4);
            *(unsigned short*)(Qs + qrow * 256 + cbyte) = bfbits(e[ni] * inv);
        }
    }
    __syncthreads();

    f32x4 accT[8];
#pragma unroll
    for (int ni = 0; ni < 8; ++ni) accT[ni] = fzero;
#pragma unroll
    for (int kk = 0; kk < 4; ++kk) {
        bf16x8 ap, bv8[8];
        {
            int row = mrow + rlo;
            ap = *reinterpret_cast<const bf16x8*>(Qs + row * 256 + ((kk * 64 + g * 16) ^ ((row & 7) << 4)));
        }
#pragma unroll
        for (int ni = 0; ni < 8; ++ni) {
            int row = ni * 16 + rlo;
            bv8[ni] = *reinterpret_cast<const bf16x8*>(Vs + row * 256 + ((kk * 64 + g * 16) ^ ((row & 7) << 4)));
        }
#pragma unroll
        for (int ni = 0; ni < 8; ++ni)
            accT[ni] = __builtin_amdgcn_mfma_f32_16x16x32_bf16(ap, bv8[ni], accT[ni], 0, 0, 0);
    }
#pragma unroll
    for (int ni = 0; ni < 8; ++ni)
#pragma unroll
        for (int r = 0; r < 4; ++r) {
            int trow = mrow + g * 4 + r;
            int cbyte = ((ni * 16 + rlo) * 2) ^ ((trow & 7) << 4);
            *(unsigned short*)(Ks + trow * 256 + cbyte) = bfbits(accT[ni][r]);
        }
    __syncthreads();

    f32x4 accC[8];
#pragma unroll
    for (int ni = 0; ni < 8; ++ni) accC[ni] = fzero;
#pragma unroll
    for (int kk = 0; kk < 4; ++kk) {
        bf16x8 at, bv8[8];
        {
            int row = mrow + rlo;
            at = *reinterpret_cast<const bf16x8*>(Ks + row * 256 + ((kk * 64 + g * 16) ^ ((row & 7) << 4)));
        }
#pragma unroll
        for (int ni = 0; ni < 8; ++ni) {
            int row = ni * 16 + rlo;
            bv8[ni] = *reinterpret_cast<const bf16x8*>(Vs + row * 256 + ((kk * 64 + g * 16) ^ ((row & 7) << 4)));
        }
#pragma unroll
        for (int ni = 0; ni < 8; ++ni)
            accC[ni] = __builtin_amdgcn_mfma_f32_16x16x32_bf16(at, bv8[ni], accC[ni], 0, 0, 0);
    }
    unsigned short* cdst = (unsigned short*)CTX;
#pragma unroll
    for (int ni = 0; ni < 8; ++ni)
#pragma unroll
        for (int r = 0; r < 4; ++r) {
            int q = mrow + g * 4 + r;
            int gm = b * 128 + q;
            int col = h * 128 + ni * 16 + rlo;
            cdst[(size_t)gm * 1024 + col] = bfbits(accC[ni][r]);
        }
}

// ---------------- layernorm over bf16 rows of 1024 -> bf16 out ----------------
__global__ __launch_bounds__(256)
void ln_k(const bf16* __restrict__ Y, const float* __restrict__ w, const float* __restrict__ b,
          bf16* __restrict__ Hb) {
    int row = blockIdx.x, tid = threadIdx.x;
    ushort4 u = reinterpret_cast<const ushort4*>(Y + (size_t)row * 1024)[tid];
    float v0 = b2f(u.x), v1 = b2f(u.y), v2 = b2f(u.z), v3 = b2f(u.w);
    float s = v0 + v1 + v2 + v3;
    float q = v0 * v0 + v1 * v1 + v2 * v2 + v3 * v3;
#pragma unroll
    for (int o = 1; o < 64; o <<= 1) { s += __shfl_xor(s, o); q += __shfl_xor(q, o); }
    __shared__ float ss[4], sq[4];
    if ((tid & 63) == 0) { ss[tid >> 6] = s; sq[tid >> 6] = q; }
    __syncthreads();
    s = ss[0] + ss[1] + ss[2] + ss[3];
    q = sq[0] + sq[1] + sq[2] + sq[3];
    float u_ = s * (1.f / 1024.f);
    float var = fmaxf(q * (1.f / 1024.f) - u_ * u_, 0.f);
    float rstd = rsqrtf(var + 1e-12f);
    float4 wv = reinterpret_cast<const float4*>(w)[tid];
    float4 bv = reinterpret_cast<const float4*>(b)[tid];
    ushort4 ob;
    ob.x = bfbits(wv.x * (v0 - u_) * rstd + bv.x);
    ob.y = bfbits(wv.y * (v1 - u_) * rstd + bv.y);
    ob.z = bfbits(wv.z * (v2 - u_) * rstd + bv.z);
    ob.w = bfbits(wv.w * (v3 - u_) * rstd + bv.w);
    reinterpret_cast<ushort4*>(Hb)[row * 256 + tid] = ob;
}

// ---- final LN: y = LN(PA + PB + b3 + resid_bf16), write f32 out ----
__global__ __launch_bounds__(256)
void ln2k(const float* __restrict__ PA, const float* __restrict__ PB,
          const float* __restrict__ b3, const bf16* __restrict__ resid,
          const float* __restrict__ w, const float* __restrict__ b,
          float* __restrict__ out) {
    int row = blockIdx.x, tid = threadIdx.x;
    size_t off = (size_t)row * 256 + tid;
    float4 pa = reinterpret_cast<const float4*>(PA)[off];
    float4 pb = reinterpret_cast<const float4*>(PB)[off];
    float4 bi = reinterpret_cast<const float4*>(b3)[tid];
    ushort4 ru = reinterpret_cast<const ushort4*>(resid)[off];
    float4 v = make_float4(pa.x + pb.x + bi.x + b2f(ru.x), pa.y + pb.y + bi.y + b2f(ru.y),
                           pa.z + pb.z + bi.z + b2f(ru.z), pa.w + pb.w + bi.w + b2f(ru.w));
    float s = v.x + v.y + v.z + v.w;
    float q = v.x * v.x + v.y * v.y + v.z * v.z + v.w * v.w;
#pragma unroll
    for (int o = 1; o < 64; o <<= 1) { s += __shfl_xor(s, o); q += __shfl_xor(q, o); }
    __shared__ float ss[4], sq[4];
    if ((tid & 63) == 0) { ss[tid >> 6] = s; sq[tid >> 6] = q; }
    __syncthreads();
    s = ss[0] + ss[1] + ss[2] + ss[3];
    q = sq[0] + sq[1] + sq[2] + sq[3];
    float u = s * (1.f / 1024.f);
    float var = fmaxf(q * (1.f / 1024.f) - u * u, 0.f);
    float rstd = rsqrtf(var + 1e-12f);
    float4 wv = reinterpret_cast<const float4*>(w)[tid];
    float4 bv = reinterpret_cast<const float4*>(b)[tid];
    float4 o4;
    o4.x = wv.x * (v.x - u) * rstd + bv.x;
    o4.y = wv.y * (v.y - u) * rstd + bv.y;
    o4.z = wv.z * (v.z - u) * rstd + bv.z;
    o4.w = wv.w * (v.w - u) * rstd + bv.w;
    reinterpret_cast<float4*>(out)[off] = o4;
}

extern "C" void kernel_launch(void* const* d_in, const int* in_sizes, int n_in,
                              void* d_out, int out_size, void* d_ws, size_t ws_size,
                              hipStream_t stream) {
    (void)in_sizes; (void)n_in; (void)out_size; (void)ws_size;
    const float* x    = (const float*)d_in[0];
    const float* Wq   = (const float*)d_in[2];
    const float* bq   = (const float*)d_in[3];
    const float* Wk   = (const float*)d_in[4];
    const float* bk   = (const float*)d_in[5];
    const float* Wv   = (const float*)d_in[6];
    const float* bv   = (const float*)d_in[7];
    const float* Wo   = (const float*)d_in[8];
    const float* bo   = (const float*)d_in[9];
    const float* ln1w = (const float*)d_in[10];
    const float* ln1b = (const float*)d_in[11];
    const float* W1   = (const float*)d_in[12];
    const float* b1   = (const float*)d_in[13];
    const float* W2   = (const float*)d_in[14];
    const float* b2   = (const float*)d_in[15];
    const float* W3   = (const float*)d_in[16];
    const float* b3   = (const float*)d_in[17];
    const float* ln2w = (const float*)d_in[18];
    const float* ln2b = (const float*)d_in[19];

    char* ws = (char*)d_ws;
    bf16*  XB    = (bf16*)(ws + 0);
    bf16*  WQKVB = (bf16*)(ws + 16777216);
    bf16*  WOB   = (bf16*)(ws + 23068672);
    bf16*  W1B   = (bf16*)(ws + 25165824);
    bf16*  W2B   = (bf16*)(ws + 29360128);
    bf16*  W3B   = (bf16*)(ws + 46137344);
    bf16*  Qb    = (bf16*)(ws + 54525952);
    bf16*  Kb    = (bf16*)(ws + 71303168);
    bf16*  VTb   = (bf16*)(ws + 88080384);    // [B,H,DK,S] (written transposed by QKV epi)
    bf16*  CTX   = (bf16*)(ws + 138412032);
    bf16*  Y2b   = (bf16*)(ws + 155189248);   // 16.8 MB bf16 (x + attn_out)
    bf16*  HB    = (bf16*)(ws + 222298112);   // LN1 out bf16 (W1 input + final residual)
    bf16*  F1    = (bf16*)(ws + 172000000 - 16810752);  // see below; use distinct region
    bf16*  F2    = (bf16*)(ws + 54525952);    // overlays Qb..VTb (dead after attn)
    float* PW3   = (float*)(ws + 121634816);  // 67 MB span; clobbers CTX (dead by W3)
    // F1 must not overlap Y2b while ln_k reads Y2b, and must be dead regions:
    // place F1 at ws+172032000 (within old H32 region 188743680? keep simple):
    F1 = (bf16*)(ws + 188743680);             // 33.5 MB region (old H32 slot, free)

    CastArgs ca;
    ca.src[0] = x;  ca.src[1] = Wq; ca.src[2] = Wk; ca.src[3] = Wv;
    ca.src[4] = Wo; ca.src[5] = W1; ca.src[6] = W2; ca.src[7] = W3;
    ca.end[0] = 2097152; ca.end[1] = 2359296; ca.end[2] = 2621440; ca.end[3] = 2883584;
    ca.end[4] = 3145728; ca.end[5] = 3670016; ca.end[6] = 5767168; ca.end[7] = 6815744;
    castall<<<2048, 256, 0, stream>>>(ca, (ushort4*)ws);

    // QKV: [8192,1024] @ [3072,1024]^T -> Q,K [B,H,S,DK], V -> VT [B,H,DK,S]
    gemm256<0, 0><<<384, 512, 0, stream>>>(XB, WQKVB, 3072, 1024, 1024,
                                           bq, bk, bv, nullptr, Qb, Kb, VTb);
    attn_fused<<<512, 512, 0, stream>>>(Qb, Kb, VTb, CTX);
    // attn_out + x(bf16) -> Y2b (bf16)
    gemm_bt<<<512, 256, 0, stream>>>(CTX, WOB, 8192, 1024, 1024, bo, XB, Y2b);
    ln_k<<<8192, 256, 0, stream>>>(Y2b, ln1w, ln1b, HB);
    // MLP
    gemm256<1, 0><<<256, 512, 0, stream>>>(HB, W1B, 2048, 1024, 1024,
                                           b1, nullptr, nullptr, (void*)F1, nullptr, nullptr, nullptr);
    gemm256<1, 0><<<512, 512, 0, stream>>>(F1, W2B, 4096, 2048, 2048,
                                           b2, nullptr, nullptr, (void*)F2, nullptr, nullptr, nullptr);
    // W3 split-K=2 -> f32 partials; reduce+bias+resid(HB)+LN fused in ln2k
    gemm256<2, 1><<<256, 512, 0, stream>>>(F2, W3B, 1024, 4096, 2048,
                                           nullptr, nullptr, nullptr, (void*)PW3, nullptr, nullptr, nullptr);
    ln2k<<<8192, 256, 0, stream>>>(PW3, PW3 + 8388608, b3, HB, ln2w, ln2b, (float*)d_out);
}

// Round 14
// 417.441 us; speedup vs baseline: 1.1149x; 1.0159x over previous
//
#include <hip/hip_runtime.h>
#include <hip/hip_bf16.h>

using bf16 = __hip_bfloat16;
typedef __attribute__((ext_vector_type(4))) float f32x4;
typedef __attribute__((ext_vector_type(8))) short bf16x8;

__device__ __forceinline__ unsigned short bfbits(float f) {
    bf16 h = __float2bfloat16(f);
    return __builtin_bit_cast(unsigned short, h);
}
__device__ __forceinline__ float b2f(unsigned short u) {
    unsigned int x = ((unsigned int)u) << 16;
    return __builtin_bit_cast(float, x);
}

__device__ __forceinline__ void g2l16(const void* g, void* l) {
    __builtin_amdgcn_global_load_lds(
        (const __attribute__((address_space(1))) unsigned int*)g,
        (__attribute__((address_space(3))) unsigned int*)l, 16, 0, 0);
}

// ---------------- fused cast f32 -> bf16 for all 8 tensors (1 launch) ----------------
struct CastArgs {
    const float* src[8];
    int end[8];   // prefix ends in float4 units; end[7] = 6815744
};
__global__ __launch_bounds__(256)
void castall(CastArgs a, ushort4* __restrict__ out) {
    int stride = gridDim.x * blockDim.x;
    for (int i = blockIdx.x * blockDim.x + threadIdx.x; i < 6815744; i += stride) {
        const float* sp; int beg;
        if      (i < a.end[0]) { sp = a.src[0]; beg = 0; }
        else if (i < a.end[1]) { sp = a.src[1]; beg = a.end[0]; }
        else if (i < a.end[2]) { sp = a.src[2]; beg = a.end[1]; }
        else if (i < a.end[3]) { sp = a.src[3]; beg = a.end[2]; }
        else if (i < a.end[4]) { sp = a.src[4]; beg = a.end[3]; }
        else if (i < a.end[5]) { sp = a.src[5]; beg = a.end[4]; }
        else if (i < a.end[6]) { sp = a.src[6]; beg = a.end[5]; }
        else                   { sp = a.src[7]; beg = a.end[6]; }
        float4 v = reinterpret_cast<const float4*>(sp)[i - beg];
        ushort4 o;
        o.x = bfbits(v.x); o.y = bfbits(v.y); o.z = bfbits(v.z); o.w = bfbits(v.w);
        out[i] = o;
    }
}

// ======= 256x256-tile 8-wave GEMM (R4-exact, best measured): ring-3, 1 barrier + vmcnt(4)/K-tile =======
// C = A @ B^T. A:[M,ldk] bf16 rm; Bm:[N,ldk] bf16 rm. BK=32, 96KB LDS ring of 3.
// EPI 0: QKV scatter (+per-tensor bias); Q,K -> [B,H,S,DK], V -> TRANSPOSED [B,H,DK,S]
// EPI 1: relu(acc+bias) -> bf16 [M,N]
// EPI 2: bf16 partials -> outp + slice*M*N  (split-K; summed in f32 by ln2k)
template<int EPI, int SPLITK>
__global__ __launch_bounds__(512, 2)
void gemm256(const bf16* __restrict__ A, const bf16* __restrict__ Bm,
             int N, int ldk, int kloop,
             const float* __restrict__ bias0, const float* __restrict__ bias1,
             const float* __restrict__ bias2,
             void* __restrict__ outp,
             bf16* __restrict__ q_o, bf16* __restrict__ k_o, bf16* __restrict__ v_o) {
    __shared__ __align__(16) char lds[98304];
    const int tid = threadIdx.x;
    const int lane = tid & 63, wave = tid >> 6;
    const int rlo = lane & 15, g = lane >> 4;
    const int wr = wave >> 2, wc = wave & 3;
    const int nbn = N >> 8;
    const int nwg = gridDim.x;
    int wg = (int)blockIdx.x;
    wg = (wg & 7) * (nwg >> 3) + (wg >> 3);   // XCD swizzle (nwg % 8 == 0)
    int slice = 0;
    if constexpr (SPLITK) {
        int half = nwg >> 1;
        slice = (wg >= half) ? 1 : 0;
        wg -= slice * half;
    }
    const int bm = wg / nbn, bn = wg % nbn;
    const size_t ldb = (size_t)ldk * 2;
    const char* abase = (const char*)A + ((size_t)bm << 8) * ldb + (size_t)slice * kloop * 2;
    const char* bbase = (const char*)Bm + ((size_t)bn << 8) * ldb + (size_t)slice * kloop * 2;

    const int P = tid * 16;
    const int R = P >> 7;
    const int qs = (P & 127) ^ ((R & 7) << 4);          // unswizzle
    const size_t goff0 = (size_t)(R * 2 + (qs >> 6)) * ldb + (qs & 63);
    const size_t ghalf = (size_t)128 * ldb;

    const int o_in = (((rlo & 1) << 6) | (g << 4)) ^ (((rlo >> 1) & 7) << 4);
    const int aoff = wr * 8192 + (rlo >> 1) * 128 + o_in;
    const int boff = 16384 + (wc >> 1) * 8192 + (wc & 1) * 4096 + (rlo >> 1) * 128 + o_in;

    const f32x4 fz = {0.f, 0.f, 0.f, 0.f};
    f32x4 acc[8][4];
#pragma unroll
    for (int i = 0; i < 8; ++i)
#pragma unroll
        for (int j = 0; j < 4; ++j) acc[i][j] = fz;

    auto stA = [&](int buf, int h, int kt) {
        g2l16(abase + goff0 + (size_t)h * ghalf + (size_t)kt * 64,
              lds + buf * 32768 + h * 8192 + P);
    };
    auto stB = [&](int buf, int h, int kt) {
        g2l16(bbase + goff0 + (size_t)h * ghalf + (size_t)kt * 64,
              lds + buf * 32768 + 16384 + h * 8192 + P);
    };

    // prologue: tiles 0,1 staged; wait tile0 (tile1's 4 stay in flight)
    stA(0, 0, 0); stA(0, 1, 0); stB(0, 0, 0); stB(0, 1, 0);
    stA(1, 0, 1); stA(1, 1, 1); stB(1, 0, 1); stB(1, 1, 1);
    asm volatile("s_waitcnt vmcnt(4)" ::: "memory");
    __builtin_amdgcn_s_barrier();
    __builtin_amdgcn_sched_barrier(0);

    const int NT = kloop >> 5;
    for (int kt = 0; kt < NT; ++kt) {
        const char* lb = lds + (kt % 3) * 32768;
        const int nbuf = (kt + 2) % 3;
        const bool pre = (kt + 2) < NT;

        bf16x8 bfr[4], afr[4];
#pragma unroll
        for (int nf = 0; nf < 4; ++nf)
            bfr[nf] = *reinterpret_cast<const bf16x8*>(lb + nf * 1024 + boff);
#pragma unroll
        for (int i = 0; i < 4; ++i)
            afr[i] = *reinterpret_cast<const bf16x8*>(lb + i * 1024 + aoff);
        if (pre) { stA(nbuf, 0, kt + 2); stA(nbuf, 1, kt + 2); }
        asm volatile("s_waitcnt lgkmcnt(0)");
        __builtin_amdgcn_s_setprio(1);
#pragma unroll
        for (int i = 0; i < 4; ++i)
#pragma unroll
            for (int nf = 0; nf < 4; ++nf)
                acc[i][nf] = __builtin_amdgcn_mfma_f32_16x16x32_bf16(afr[i], bfr[nf], acc[i][nf], 0, 0, 0);
        __builtin_amdgcn_s_setprio(0);

#pragma unroll
        for (int i = 0; i < 4; ++i)
            afr[i] = *reinterpret_cast<const bf16x8*>(lb + (4 + i) * 1024 + aoff);
        if (pre) { stB(nbuf, 0, kt + 2); stB(nbuf, 1, kt + 2); }
        asm volatile("s_waitcnt lgkmcnt(0)");
        __builtin_amdgcn_s_setprio(1);
#pragma unroll
        for (int i = 0; i < 4; ++i)
#pragma unroll
            for (int nf = 0; nf < 4; ++nf)
                acc[4 + i][nf] = __builtin_amdgcn_mfma_f32_16x16x32_bf16(afr[i], bfr[nf], acc[4 + i][nf], 0, 0, 0);
        __builtin_amdgcn_s_setprio(0);

        if (pre) {
            asm volatile("s_waitcnt vmcnt(4)" ::: "memory");   // tile kt+1 landed
        } else if (kt + 1 < NT) {
            asm volatile("s_waitcnt vmcnt(0)" ::: "memory");
        }
        if (kt + 1 < NT) {
            __builtin_amdgcn_s_barrier();
            __builtin_amdgcn_sched_barrier(0);
        }
    }

    const int gm0 = (bm << 8) + wr * 128;
    const int gn0 = (bn << 8) + wc * 64;
#pragma unroll
    for (int mf = 0; mf < 8; ++mf) {
#pragma unroll
        for (int nf = 0; nf < 4; ++nf) {
            const int gnc = gn0 + nf * 16 + rlo;
#pragma unroll
            for (int r = 0; r < 4; ++r) {
                const int gmr = gm0 + mf * 16 + g * 4 + r;
                float val = acc[mf][nf][r];
                if constexpr (EPI == 0) {
                    int t = gnc >> 10;
                    const float* bp = (t == 0) ? bias0 : ((t == 1) ? bias1 : bias2);
                    val += bp[gnc & 1023];
                    bf16* dst = (t == 0) ? q_o : ((t == 1) ? k_o : v_o);
                    int hh = (gnc >> 7) & 7, d = gnc & 127;
                    int bb = gmr >> 7, s = gmr & 127;
                    size_t idx = (t == 2)
                        ? ((((size_t)bb * 8 + hh) * 128 + d) * 128 + s)   // V stored transposed
                        : ((((size_t)bb * 8 + hh) * 128 + s) * 128 + d);
                    dst[idx] = __float2bfloat16(val);
                } else if constexpr (EPI == 1) {
                    val = fmaxf(val + bias0[gnc], 0.f);
                    ((bf16*)outp)[(size_t)gmr * N + gnc] = __float2bfloat16(val);
                } else {
                    bf16* pp = (bf16*)outp + (size_t)slice * 8388608;
                    pp[(size_t)gmr * N + gnc] = __float2bfloat16(val);
                }
            }
        }
    }
}

// ---------------- GEMM: C = A @ B^T, 128^2 tile (Wo, N=1024) ----------------
// EPI: acc + bias + resid(bf16) -> bf16 out (Y2 path all-bf16)
__global__ __launch_bounds__(256, 2)
void gemm_bt(const bf16* __restrict__ A, const bf16* __restrict__ Bm,
             int M, int N, int K,
             const float* __restrict__ bias0, const bf16* __restrict__ resid,
             bf16* __restrict__ outp) {
    (void)M;
    __shared__ __align__(16) char As[8192];
    __shared__ __align__(16) char Bs[8192];
    int tid = threadIdx.x, wave = tid >> 6, lane = tid & 63;
    int nbn = N >> 7;
    int bm = blockIdx.x / nbn, bn = blockIdx.x % nbn;
    int wm = (wave >> 1) << 6, wn = (wave & 1) << 6;
    int rlo = lane & 15, g = lane >> 4;

    const char* abase = (const char*)(A + (size_t)(bm << 7) * K);
    const char* bbase = (const char*)(Bm + (size_t)(bn << 7) * K);

    const f32x4 fzero = {0.f, 0.f, 0.f, 0.f};
    f32x4 acc[4][4];
#pragma unroll
    for (int i = 0; i < 4; ++i)
#pragma unroll
        for (int j = 0; j < 4; ++j) acc[i][j] = fzero;

    int L0 = wave * 2048 + lane * 16;
    size_t ldbyte = (size_t)K * 2;

    for (int k0 = 0; k0 < K; k0 += 32) {
#pragma unroll
        for (int j = 0; j < 2; ++j) {
            int L = L0 + j * 1024;
            int row = L >> 6;
            int cb = (L & 63) ^ (((row >> 1) & 3) << 4);
            g2l16(abase + (size_t)row * ldbyte + (size_t)k0 * 2 + cb, As + wave * 2048 + j * 1024);
            g2l16(bbase + (size_t)row * ldbyte + (size_t)k0 * 2 + cb, Bs + wave * 2048 + j * 1024);
        }
        __syncthreads();
        bf16x8 af[4], bf8[4];
#pragma unroll
        for (int i = 0; i < 4; ++i) {
            int ra = wm + i * 16 + rlo;
            af[i] = *reinterpret_cast<const bf16x8*>(As + ra * 64 + ((g * 16) ^ (((ra >> 1) & 3) << 4)));
            int rb = wn + i * 16 + rlo;
            bf8[i] = *reinterpret_cast<const bf16x8*>(Bs + rb * 64 + ((g * 16) ^ (((rb >> 1) & 3) << 4)));
        }
#pragma unroll
        for (int mi = 0; mi < 4; ++mi)
#pragma unroll
            for (int ni = 0; ni < 4; ++ni)
                acc[mi][ni] = __builtin_amdgcn_mfma_f32_16x16x32_bf16(af[mi], bf8[ni], acc[mi][ni], 0, 0, 0);
        __syncthreads();
    }

    int gm0 = (bm << 7) + wm, gn0 = (bn << 7) + wn;
#pragma unroll
    for (int mi = 0; mi < 4; ++mi) {
#pragma unroll
        for (int ni = 0; ni < 4; ++ni) {
            int gnc = gn0 + ni * 16 + rlo;
#pragma unroll
            for (int r = 0; r < 4; ++r) {
                int gmr = gm0 + mi * 16 + g * 4 + r;
                size_t idx = (size_t)gmr * N + gnc;
                float val = acc[mi][ni][r] + bias0[gnc] +
                            b2f(__builtin_bit_cast(unsigned short, resid[idx]));
                outp[idx] = __float2bfloat16(val);
            }
        }
    }
}

// ---------------- fused attention per (b,h), 8 waves: CTX = (softmax(QK^T/s) @ V) @ V ----------------
__global__ __launch_bounds__(512, 1)
void attn_fused(const bf16* __restrict__ Q, const bf16* __restrict__ K,
                const bf16* __restrict__ VT, bf16* __restrict__ CTX) {
    __shared__ __align__(16) char Qs[32768];
    __shared__ __align__(16) char Ks[32768];
    __shared__ __align__(16) char Vs[32768];
    int bh = blockIdx.x, b = bh >> 3, h = bh & 7;
    int tid = threadIdx.x, wave = tid >> 6, lane = tid & 63;
    const char* qsrc = (const char*)(Q + (size_t)bh * 16384);
    const char* ksrc = (const char*)(K + (size_t)bh * 16384);
    const char* vsrc = (const char*)(VT + (size_t)bh * 16384);
#pragma unroll
    for (int j = 0; j < 4; ++j) {
        int L = j * 8192 + tid * 16;
        int row = L >> 8;
        int cb = (L & 255) ^ ((row & 7) << 4);
        g2l16(qsrc + row * 256 + cb, Qs + j * 8192 + tid * 16);
        g2l16(ksrc + row * 256 + cb, Ks + j * 8192 + tid * 16);
        g2l16(vsrc + row * 256 + cb, Vs + j * 8192 + tid * 16);
    }
    __syncthreads();
    int rlo = lane & 15, g = lane >> 4;
    const f32x4 fzero = {0.f, 0.f, 0.f, 0.f};
    const int mrow = wave * 16;

    f32x4 acc[8];
#pragma unroll
    for (int ni = 0; ni < 8; ++ni) acc[ni] = fzero;
#pragma unroll
    for (int kk = 0; kk < 4; ++kk) {
        bf16x8 aq, bk8[8];
        {
            int row = mrow + rlo;
            aq = *reinterpret_cast<const bf16x8*>(Qs + row * 256 + ((kk * 64 + g * 16) ^ ((row & 7) << 4)));
        }
#pragma unroll
        for (int ni = 0; ni < 8; ++ni) {
            int row = ni * 16 + rlo;
            bk8[ni] = *reinterpret_cast<const bf16x8*>(Ks + row * 256 + ((kk * 64 + g * 16) ^ ((row & 7) << 4)));
        }
#pragma unroll
        for (int ni = 0; ni < 8; ++ni)
            acc[ni] = __builtin_amdgcn_mfma_f32_16x16x32_bf16(aq, bk8[ni], acc[ni], 0, 0, 0);
    }

    const float scale = 0.088388347648318447f;  // 1/sqrt(128)
#pragma unroll
    for (int r = 0; r < 4; ++r) {
        float m = -3e38f;
#pragma unroll
        for (int ni = 0; ni < 8; ++ni) m = fmaxf(m, acc[ni][r]);
#pragma unroll
        for (int o = 1; o < 16; o <<= 1) m = fmaxf(m, __shfl_xor(m, o));
        m *= scale;
        float e[8];
        float sum = 0.f;
#pragma unroll
        for (int ni = 0; ni < 8; ++ni) { e[ni] = __expf(acc[ni][r] * scale - m); sum += e[ni]; }
#pragma unroll
        for (int o = 1; o < 16; o <<= 1) sum += __shfl_xor(sum, o);
        float inv = 1.f / sum;
        int qrow = mrow + g * 4 + r;
#pragma unroll
        for (int ni = 0; ni < 8; ++ni) {
            int cbyte = ((ni * 16 + rlo) * 2) ^ ((qrow & 7) << 4);
            *(unsigned short*)(Qs + qrow * 256 + cbyte) = bfbits(e[ni] * inv);
        }
    }
    __syncthreads();

    f32x4 accT[8];
#pragma unroll
    for (int ni = 0; ni < 8; ++ni) accT[ni] = fzero;
#pragma unroll
    for (int kk = 0; kk < 4; ++kk) {
        bf16x8 ap, bv8[8];
        {
            int row = mrow + rlo;
            ap = *reinterpret_cast<const bf16x8*>(Qs + row * 256 + ((kk * 64 + g * 16) ^ ((row & 7) << 4)));
        }
#pragma unroll
        for (int ni = 0; ni < 8; ++ni) {
            int row = ni * 16 + rlo;
            bv8[ni] = *reinterpret_cast<const bf16x8*>(Vs + row * 256 + ((kk * 64 + g * 16) ^ ((row & 7) << 4)));
        }
#pragma unroll
        for (int ni = 0; ni < 8; ++ni)
            accT[ni] = __builtin_amdgcn_mfma_f32_16x16x32_bf16(ap, bv8[ni], accT[ni], 0, 0, 0);
    }
#pragma unroll
    for (int ni = 0; ni < 8; ++ni)
#pragma unroll
        for (int r = 0; r < 4; ++r) {
            int trow = mrow + g * 4 + r;
            int cbyte = ((ni * 16 + rlo) * 2) ^ ((trow & 7) << 4);
            *(unsigned short*)(Ks + trow * 256 + cbyte) = bfbits(accT[ni][r]);
        }
    __syncthreads();

    f32x4 accC[8];
#pragma unroll
    for (int ni = 0; ni < 8; ++ni) accC[ni] = fzero;
#pragma unroll
    for (int kk = 0; kk < 4; ++kk) {
        bf16x8 at, bv8[8];
        {
            int row = mrow + rlo;
            at = *reinterpret_cast<const bf16x8*>(Ks + row * 256 + ((kk * 64 + g * 16) ^ ((row & 7) << 4)));
        }
#pragma unroll
        for (int ni = 0; ni < 8; ++ni) {
            int row = ni * 16 + rlo;
            bv8[ni] = *reinterpret_cast<const bf16x8*>(Vs + row * 256 + ((kk * 64 + g * 16) ^ ((row & 7) << 4)));
        }
#pragma unroll
        for (int ni = 0; ni < 8; ++ni)
            accC[ni] = __builtin_amdgcn_mfma_f32_16x16x32_bf16(at, bv8[ni], accC[ni], 0, 0, 0);
    }
    unsigned short* cdst = (unsigned short*)CTX;
#pragma unroll
    for (int ni = 0; ni < 8; ++ni)
#pragma unroll
        for (int r = 0; r < 4; ++r) {
            int q = mrow + g * 4 + r;
            int gm = b * 128 + q;
            int col = h * 128 + ni * 16 + rlo;
            cdst[(size_t)gm * 1024 + col] = bfbits(accC[ni][r]);
        }
}

// ---------------- layernorm over bf16 rows of 1024 -> bf16 out ----------------
__global__ __launch_bounds__(256)
void ln_k(const bf16* __restrict__ Y, const float* __restrict__ w, const float* __restrict__ b,
          bf16* __restrict__ Hb) {
    int row = blockIdx.x, tid = threadIdx.x;
    ushort4 u = reinterpret_cast<const ushort4*>(Y + (size_t)row * 1024)[tid];
    float v0 = b2f(u.x), v1 = b2f(u.y), v2 = b2f(u.z), v3 = b2f(u.w);
    float s = v0 + v1 + v2 + v3;
    float q = v0 * v0 + v1 * v1 + v2 * v2 + v3 * v3;
#pragma unroll
    for (int o = 1; o < 64; o <<= 1) { s += __shfl_xor(s, o); q += __shfl_xor(q, o); }
    __shared__ float ss[4], sq[4];
    if ((tid & 63) == 0) { ss[tid >> 6] = s; sq[tid >> 6] = q; }
    __syncthreads();
    s = ss[0] + ss[1] + ss[2] + ss[3];
    q = sq[0] + sq[1] + sq[2] + sq[3];
    float u_ = s * (1.f / 1024.f);
    float var = fmaxf(q * (1.f / 1024.f) - u_ * u_, 0.f);
    float rstd = rsqrtf(var + 1e-12f);
    float4 wv = reinterpret_cast<const float4*>(w)[tid];
    float4 bv = reinterpret_cast<const float4*>(b)[tid];
    ushort4 ob;
    ob.x = bfbits(wv.x * (v0 - u_) * rstd + bv.x);
    ob.y = bfbits(wv.y * (v1 - u_) * rstd + bv.y);
    ob.z = bfbits(wv.z * (v2 - u_) * rstd + bv.z);
    ob.w = bfbits(wv.w * (v3 - u_) * rstd + bv.w);
    reinterpret_cast<ushort4*>(Hb)[row * 256 + tid] = ob;
}

// ---- final LN: y = LN(PA + PB + b3 + resid_bf16), write f32 out. PA/PB bf16 partials ----
__global__ __launch_bounds__(256)
void ln2k(const bf16* __restrict__ PA, const bf16* __restrict__ PB,
          const float* __restrict__ b3, const bf16* __restrict__ resid,
          const float* __restrict__ w, const float* __restrict__ b,
          float* __restrict__ out) {
    int row = blockIdx.x, tid = threadIdx.x;
    size_t off = (size_t)row * 256 + tid;
    ushort4 pa = reinterpret_cast<const ushort4*>(PA)[off];
    ushort4 pb = reinterpret_cast<const ushort4*>(PB)[off];
    float4 bi = reinterpret_cast<const float4*>(b3)[tid];
    ushort4 ru = reinterpret_cast<const ushort4*>(resid)[off];
    float4 v = make_float4(b2f(pa.x) + b2f(pb.x) + bi.x + b2f(ru.x),
                           b2f(pa.y) + b2f(pb.y) + bi.y + b2f(ru.y),
                           b2f(pa.z) + b2f(pb.z) + bi.z + b2f(ru.z),
                           b2f(pa.w) + b2f(pb.w) + bi.w + b2f(ru.w));
    float s = v.x + v.y + v.z + v.w;
    float q = v.x * v.x + v.y * v.y + v.z * v.z + v.w * v.w;
#pragma unroll
    for (int o = 1; o < 64; o <<= 1) { s += __shfl_xor(s, o); q += __shfl_xor(q, o); }
    __shared__ float ss[4], sq[4];
    if ((tid & 63) == 0) { ss[tid >> 6] = s; sq[tid >> 6] = q; }
    __syncthreads();
    s = ss[0] + ss[1] + ss[2] + ss[3];
    q = sq[0] + sq[1] + sq[2] + sq[3];
    float u = s * (1.f / 1024.f);
    float var = fmaxf(q * (1.f / 1024.f) - u * u, 0.f);
    float rstd = rsqrtf(var + 1e-12f);
    float4 wv = reinterpret_cast<const float4*>(w)[tid];
    float4 bv = reinterpret_cast<const float4*>(b)[tid];
    float4 o4;
    o4.x = wv.x * (v.x - u) * rstd + bv.x;
    o4.y = wv.y * (v.y - u) * rstd + bv.y;
    o4.z = wv.z * (v.z - u) * rstd + bv.z;
    o4.w = wv.w * (v.w - u) * rstd + bv.w;
    reinterpret_cast<float4*>(out)[off] = o4;
}

extern "C" void kernel_launch(void* const* d_in, const int* in_sizes, int n_in,
                              void* d_out, int out_size, void* d_ws, size_t ws_size,
                              hipStream_t stream) {
    (void)in_sizes; (void)n_in; (void)out_size; (void)ws_size;
    const float* x    = (const float*)d_in[0];
    const float* Wq   = (const float*)d_in[2];
    const float* bq   = (const float*)d_in[3];
    const float* Wk   = (const float*)d_in[4];
    const float* bk   = (const float*)d_in[5];
    const float* Wv   = (const float*)d_in[6];
    const float* bv   = (const float*)d_in[7];
    const float* Wo   = (const float*)d_in[8];
    const float* bo   = (const float*)d_in[9];
    const float* ln1w = (const float*)d_in[10];
    const float* ln1b = (const float*)d_in[11];
    const float* W1   = (const float*)d_in[12];
    const float* b1   = (const float*)d_in[13];
    const float* W2   = (const float*)d_in[14];
    const float* b2   = (const float*)d_in[15];
    const float* W3   = (const float*)d_in[16];
    const float* b3   = (const float*)d_in[17];
    const float* ln2w = (const float*)d_in[18];
    const float* ln2b = (const float*)d_in[19];

    char* ws = (char*)d_ws;
    bf16*  XB    = (bf16*)(ws + 0);
    bf16*  WQKVB = (bf16*)(ws + 16777216);
    bf16*  WOB   = (bf16*)(ws + 23068672);
    bf16*  W1B   = (bf16*)(ws + 25165824);
    bf16*  W2B   = (bf16*)(ws + 29360128);
    bf16*  W3B   = (bf16*)(ws + 46137344);
    bf16*  Qb    = (bf16*)(ws + 54525952);
    bf16*  Kb    = (bf16*)(ws + 71303168);
    bf16*  VTb   = (bf16*)(ws + 88080384);    // [B,H,DK,S] (written transposed by QKV epi)
    bf16*  CTX   = (bf16*)(ws + 138412032);
    bf16*  Y2b   = (bf16*)(ws + 155189248);   // 16.8 MB bf16 (x + attn_out)
    bf16*  HB    = (bf16*)(ws + 222298112);   // LN1 out bf16 (W1 input + final residual)
    bf16*  F1    = (bf16*)(ws + 188743680);   // 33.5 MB region (free)
    bf16*  F2    = (bf16*)(ws + 54525952);    // overlays Qb..VTb (dead after attn)
    bf16*  PW3   = (bf16*)(ws + 121634816);   // 33.5 MB = 2 slices x 16.8 MB (Pb/CTX slots dead)

    CastArgs ca;
    ca.src[0] = x;  ca.src[1] = Wq; ca.src[2] = Wk; ca.src[3] = Wv;
    ca.src[4] = Wo; ca.src[5] = W1; ca.src[6] = W2; ca.src[7] = W3;
    ca.end[0] = 2097152; ca.end[1] = 2359296; ca.end[2] = 2621440; ca.end[3] = 2883584;
    ca.end[4] = 3145728; ca.end[5] = 3670016; ca.end[6] = 5767168; ca.end[7] = 6815744;
    castall<<<2048, 256, 0, stream>>>(ca, (ushort4*)ws);

    // QKV: [8192,1024] @ [3072,1024]^T -> Q,K [B,H,S,DK], V -> VT [B,H,DK,S]
    gemm256<0, 0><<<384, 512, 0, stream>>>(XB, WQKVB, 3072, 1024, 1024,
                                           bq, bk, bv, nullptr, Qb, Kb, VTb);
    attn_fused<<<512, 512, 0, stream>>>(Qb, Kb, VTb, CTX);
    // attn_out + x(bf16) -> Y2b (bf16)
    gemm_bt<<<512, 256, 0, stream>>>(CTX, WOB, 8192, 1024, 1024, bo, XB, Y2b);
    ln_k<<<8192, 256, 0, stream>>>(Y2b, ln1w, ln1b, HB);
    // MLP
    gemm256<1, 0><<<256, 512, 0, stream>>>(HB, W1B, 2048, 1024, 1024,
                                           b1, nullptr, nullptr, (void*)F1, nullptr, nullptr, nullptr);
    gemm256<1, 0><<<512, 512, 0, stream>>>(F1, W2B, 4096, 2048, 2048,
                                           b2, nullptr, nullptr, (void*)F2, nullptr, nullptr, nullptr);
    // W3 split-K=2 -> bf16 partials; reduce(f32)+bias+resid(HB)+LN fused in ln2k
    gemm256<2, 1><<<256, 512, 0, stream>>>(F2, W3B, 1024, 4096, 2048,
                                           nullptr, nullptr, nullptr, (void*)PW3, nullptr, nullptr, nullptr);
    ln2k<<<8192, 256, 0, stream>>>(PW3, PW3 + 8388608, b3, HB, ln2w, ln2b, (float*)d_out);
}